// Round 5
// baseline (201.891 us; speedup 1.0000x reference)
//
#include <hip/hip_runtime.h>
#include <hip/hip_bf16.h>
#include <cstdint>

#define C_DIM 1024
#define L_DIM 2048
#define N_DIM 4
#define M_DIM (N_DIM * L_DIM)   // 8192

typedef __attribute__((ext_vector_type(8))) short frag8;    // 8 bf16 = 4 VGPRs
typedef __attribute__((ext_vector_type(4)))  float f32x4;
typedef __attribute__((ext_vector_type(16))) float f32x16;

// ---------------- helpers ----------------
__device__ __forceinline__ void gl_lds16(const void* g, void* l) {
  __builtin_amdgcn_global_load_lds((const __attribute__((address_space(1))) void*)g,
                                   (__attribute__((address_space(3))) void*)l,
                                   16, 0, 0);
}
__device__ __forceinline__ void store_out(float* Y, size_t idx, float v) { Y[idx] = v; }
__device__ __forceinline__ void store_out(__hip_bfloat16* Y, size_t idx, float v) {
  Y[idx] = __float2bfloat16(v);
}
__device__ __forceinline__ float4 ldbf4(const __hip_bfloat16* p) {
  union { short4 s; __hip_bfloat16 h[4]; } u; u.s = *(const short4*)p;
  return make_float4((float)u.h[0], (float)u.h[1], (float)u.h[2], (float)u.h[3]);
}
__device__ __forceinline__ void stbf4(__hip_bfloat16* p, float4 v) {
  union { short4 s; __hip_bfloat16 h[4]; } u;
  u.h[0] = __float2bfloat16(v.x); u.h[1] = __float2bfloat16(v.y);
  u.h[2] = __float2bfloat16(v.z); u.h[3] = __float2bfloat16(v.w);
  *(short4*)p = u.s;
}
// fast GELU (tanh form)
__device__ __forceinline__ float gelu_fast(float t) {
  const float t3 = t * t * t;
  const float ns = -1.5957691216f * t - 0.0713548163f * t3;
  return t / (1.f + __expf(ns));
}

// fp32 -> bf16 bulk convert, 8 elems/thread
__global__ __launch_bounds__(256)
void cvt_f32_bf16(const float* __restrict__ in, __hip_bfloat16* __restrict__ out, int n8) {
  const int i = blockIdx.x * 256 + threadIdx.x;
  if (i >= n8) return;
  const float4 a = *(const float4*)(in + (size_t)i * 8);
  const float4 b = *(const float4*)(in + (size_t)i * 8 + 4);
  union { __hip_bfloat16 h[8]; int4 q; } u;
  u.h[0] = __float2bfloat16(a.x); u.h[1] = __float2bfloat16(a.y);
  u.h[2] = __float2bfloat16(a.z); u.h[3] = __float2bfloat16(a.w);
  u.h[4] = __float2bfloat16(b.x); u.h[5] = __float2bfloat16(b.y);
  u.h[6] = __float2bfloat16(b.z); u.h[7] = __float2bfloat16(b.w);
  *(int4*)(out + (size_t)i * 8) = u.q;
}

// two tensors in one launch (fallback path)
__global__ __launch_bounds__(256)
void cvt_two_f32_bf16(const float* __restrict__ inA, __hip_bfloat16* __restrict__ outA,
                      const float* __restrict__ inB, __hip_bfloat16* __restrict__ outB,
                      int n8each) {
  int i = blockIdx.x * 256 + threadIdx.x;
  const float* in; __hip_bfloat16* out;
  if (i < n8each) { in = inA; out = outA; }
  else            { in = inB; out = outB; i -= n8each; }
  if (i >= n8each) return;
  const float4 a = *(const float4*)(in + (size_t)i * 8);
  const float4 b = *(const float4*)(in + (size_t)i * 8 + 4);
  union { __hip_bfloat16 h[8]; int4 q; } u;
  u.h[0] = __float2bfloat16(a.x); u.h[1] = __float2bfloat16(a.y);
  u.h[2] = __float2bfloat16(a.z); u.h[3] = __float2bfloat16(a.w);
  u.h[4] = __float2bfloat16(b.x); u.h[5] = __float2bfloat16(b.y);
  u.h[6] = __float2bfloat16(b.z); u.h[7] = __float2bfloat16(b.w);
  *(int4*)(out + (size_t)i * 8) = u.q;
}

// ---- cvt_trans_wi: Wi[j][k] f32 -> WiT[k][j] bf16 (tiled LDS transpose) ----
// 64x64 tiles, grid (16,16). 2-way-max LDS bank aliasing (free).
__global__ __launch_bounds__(256)
void cvt_trans_wi(const float* __restrict__ Wi, __hip_bfloat16* __restrict__ WiT) {
  __shared__ float tile[64][65];
  const int bi = blockIdx.x;     // j block
  const int bj = blockIdx.y;     // k block
  const int t  = threadIdx.x;
  const int r  = t >> 2;          // 0..63
  const int c0 = (t & 3) * 16;    // 0,16,32,48
  const float* src = Wi + (size_t)(bi * 64 + r) * C_DIM + bj * 64 + c0;
  *(float4*)&tile[r][c0]      = *(const float4*)(src);
  *(float4*)&tile[r][c0 + 4]  = *(const float4*)(src + 4);
  *(float4*)&tile[r][c0 + 8]  = *(const float4*)(src + 8);
  *(float4*)&tile[r][c0 + 12] = *(const float4*)(src + 12);
  __syncthreads();
  const int kr = t >> 2, j0 = (t & 3) * 16;
  __hip_bfloat16* dst = WiT + (size_t)(bj * 64 + kr) * C_DIM + bi * 64 + j0;
  union { __hip_bfloat16 h[16]; int4 q[2]; } u;
#pragma unroll
  for (int i = 0; i < 16; i++) u.h[i] = __float2bfloat16(tile[j0 + i][kr]);
  *(int4*)(dst)     = u.q[0];
  *(int4*)(dst + 8) = u.q[1];
}

// ---- cvt_wout_bvec: Wout->bf16 (blocks 0..511) + bvec = Wout@bi (512..767) ----
__global__ __launch_bounds__(256)
void cvt_wout_bvec(const float* __restrict__ Wout, __hip_bfloat16* __restrict__ Woutb,
                   const float* __restrict__ bi, float* __restrict__ bvec) {
  const int b = blockIdx.x;
  if (b < 512) {
    const int i = b * 256 + threadIdx.x;   // < 131072 = WE/8
    const float4 a = *(const float4*)(Wout + (size_t)i * 8);
    const float4 c = *(const float4*)(Wout + (size_t)i * 8 + 4);
    union { __hip_bfloat16 h[8]; int4 q; } u;
    u.h[0] = __float2bfloat16(a.x); u.h[1] = __float2bfloat16(a.y);
    u.h[2] = __float2bfloat16(a.z); u.h[3] = __float2bfloat16(a.w);
    u.h[4] = __float2bfloat16(c.x); u.h[5] = __float2bfloat16(c.y);
    u.h[6] = __float2bfloat16(c.z); u.h[7] = __float2bfloat16(c.w);
    *(int4*)(Woutb + (size_t)i * 8) = u.q;
  } else {
    const int row  = (b - 512) * 4 + (threadIdx.x >> 6);
    const int lane = threadIdx.x & 63;
    const float* wr = Wout + (size_t)row * C_DIM;
    float s = 0.f;
#pragma unroll
    for (int c = 0; c < 4; c++) {
      const int j = c * 256 + lane * 4;
      const float4 w  = *(const float4*)(wr + j);
      const float4 bb = *(const float4*)(bi + j);
      s += w.x * bb.x + w.y * bb.y + w.z * bb.z + w.w * bb.w;
    }
#pragma unroll
    for (int m = 1; m < 64; m <<= 1) s += __shfl_xor(s, m);
    if (lane == 0) bvec[row] = s;
  }
}

// ------- GEMM: BK=64, double-buffered LDS, 32x32x16 MFMA, 1 barrier/iter -------
// Y[M,N] = X[M,K] @ W[N,K]^T (+ bias[col]) (+ sArr[row]*bvec[col]).
template <typename TY>
__global__ __launch_bounds__(256, 2)
void gemm_db(const __hip_bfloat16* __restrict__ X,
             const __hip_bfloat16* __restrict__ W,
             const float* __restrict__ bias,
             TY* __restrict__ Y, int M, int N, int K,
             const float* __restrict__ sArr, const float* __restrict__ bvec)
{
  __shared__ __hip_bfloat16 As[2][2][128 * 32];   // [buf][panel]
  __shared__ __hip_bfloat16 Bs[2][2][128 * 32];
  const int tid  = threadIdx.x;
  const int lane = tid & 63;
  const int wave = tid >> 6;
  const int bm = blockIdx.x * 128;
  const int bn = blockIdx.y * 128;
  const int wr = (wave >> 1) * 64;
  const int wc = (wave & 1) * 64;
  const int srow  = tid >> 2;       // 0..63
  const int skoff = (tid & 3) * 8;  // elements

  const __hip_bfloat16* gA0 = X + (size_t)(bm + srow) * K + skoff;
  const __hip_bfloat16* gA1 = X + (size_t)(bm + 64 + srow) * K + skoff;
  const __hip_bfloat16* gB0 = W + (size_t)(bn + srow) * K + skoff;
  const __hip_bfloat16* gB1 = W + (size_t)(bn + 64 + srow) * K + skoff;

  f32x16 acc[2][2] = {};
  const int arow  = lane & 31;
  const int akoff = (lane >> 5) * 8;

#define STAGE(k0, buf)                                        \
  do {                                                        \
    gl_lds16(gA0 + (k0),      &As[buf][0][tid * 8]);          \
    gl_lds16(gA1 + (k0),      &As[buf][0][2048 + tid * 8]);   \
    gl_lds16(gA0 + (k0) + 32, &As[buf][1][tid * 8]);          \
    gl_lds16(gA1 + (k0) + 32, &As[buf][1][2048 + tid * 8]);   \
    gl_lds16(gB0 + (k0),      &Bs[buf][0][tid * 8]);          \
    gl_lds16(gB1 + (k0),      &Bs[buf][0][2048 + tid * 8]);   \
    gl_lds16(gB0 + (k0) + 32, &Bs[buf][1][tid * 8]);          \
    gl_lds16(gB1 + (k0) + 32, &Bs[buf][1][2048 + tid * 8]);   \
  } while (0)

  STAGE(0, 0);
  __syncthreads();
  const int iters = K / 64;
  for (int it = 0; it < iters; ++it) {
    const int cur = it & 1;
    if (it + 1 < iters) STAGE((it + 1) * 64, cur ^ 1);   // prefetch next tile

#pragma unroll
    for (int p = 0; p < 2; ++p)
#pragma unroll
      for (int h = 0; h < 2; ++h) {
        const frag8 a0 = *(const frag8*)&As[cur][p][(wr + arow) * 32 + h * 16 + akoff];
        const frag8 a1 = *(const frag8*)&As[cur][p][(wr + 32 + arow) * 32 + h * 16 + akoff];
        const frag8 b0 = *(const frag8*)&Bs[cur][p][(wc + arow) * 32 + h * 16 + akoff];
        const frag8 b1 = *(const frag8*)&Bs[cur][p][(wc + 32 + arow) * 32 + h * 16 + akoff];
        acc[0][0] = __builtin_amdgcn_mfma_f32_32x32x16_bf16(a0, b0, acc[0][0], 0, 0, 0);
        acc[0][1] = __builtin_amdgcn_mfma_f32_32x32x16_bf16(a0, b1, acc[0][1], 0, 0, 0);
        acc[1][0] = __builtin_amdgcn_mfma_f32_32x32x16_bf16(a1, b0, acc[1][0], 0, 0, 0);
        acc[1][1] = __builtin_amdgcn_mfma_f32_32x32x16_bf16(a1, b1, acc[1][1], 0, 0, 0);
      }
    __syncthreads();   // drains prefetch loads + protects buf reuse
  }
#undef STAGE

  // C/D layout (32x32): col=lane&31, row=(r&3)+8*(r>>2)+4*(lane>>5)  [m74/m101]
#pragma unroll
  for (int i = 0; i < 2; i++)
#pragma unroll
    for (int j = 0; j < 2; j++) {
      const int col = bn + wc + j * 32 + (lane & 31);
      const float bv  = bias ? bias[col] : 0.f;
      const float bvv = (sArr && bvec) ? bvec[col] : 0.f;
#pragma unroll
      for (int r = 0; r < 16; r++) {
        const int row = bm + wr + i * 32 + (r & 3) + 8 * (r >> 2) + 4 * (lane >> 5);
        float extra = bv;
        if (sArr) extra += sArr[row] * bvv;
        store_out(Y, (size_t)row * N + col, acc[i][j][r] + extra);
      }
    }
}

// ---------------- fallback GEMM (16x16, register staging) ----------------
struct Ld8f { float4 a, b; };
struct Ld8b { int4 a; };
__device__ __forceinline__ Ld8f ld8(const float* p) {
  return { *(const float4*)p, *(const float4*)(p + 4) };
}
__device__ __forceinline__ Ld8b ld8(const __hip_bfloat16* p) { return { *(const int4*)p }; }
__device__ __forceinline__ void st8(__hip_bfloat16* l, const Ld8f& v) {
  union { __hip_bfloat16 h[8]; int4 q; } u;
  u.h[0] = __float2bfloat16(v.a.x); u.h[1] = __float2bfloat16(v.a.y);
  u.h[2] = __float2bfloat16(v.a.z); u.h[3] = __float2bfloat16(v.a.w);
  u.h[4] = __float2bfloat16(v.b.x); u.h[5] = __float2bfloat16(v.b.y);
  u.h[6] = __float2bfloat16(v.b.z); u.h[7] = __float2bfloat16(v.b.w);
  *(int4*)l = u.q;
}
__device__ __forceinline__ void st8(__hip_bfloat16* l, const Ld8b& v) { *(int4*)l = v.a; }

template <typename TX, typename TY>
__global__ __launch_bounds__(256, 2)
void gemm_nt(const TX* __restrict__ X, const float* __restrict__ W,
             const float* __restrict__ bias, TY* __restrict__ Y, int M, int N, int K)
{
  __shared__ __hip_bfloat16 As[128 * 32];
  __shared__ __hip_bfloat16 Bs[128 * 32];
  const int tid  = threadIdx.x;
  const int lane = tid & 63;
  const int wave = tid >> 6;
  const int bm = blockIdx.x * 128;
  const int bn = blockIdx.y * 128;
  const int wr = (wave >> 1) * 64;
  const int wc = (wave & 1) * 64;
  const int srow  = tid >> 2;
  const int skoff = (tid & 3) * 8;

  f32x4 acc[4][4] = {};
  const TX*    gA0 = X + (size_t)(bm + srow) * K + skoff;
  const TX*    gA1 = X + (size_t)(bm + 64 + srow) * K + skoff;
  const float* gB0 = W + (size_t)(bn + srow) * K + skoff;
  const float* gB1 = W + (size_t)(bn + 64 + srow) * K + skoff;
  const int arow  = lane & 15;
  const int akoff = (lane >> 4) * 8;

  for (int k0 = 0; k0 < K; k0 += 32) {
    const auto va0 = ld8(gA0 + k0);
    const auto va1 = ld8(gA1 + k0);
    const auto vb0 = ld8(gB0 + k0);
    const auto vb1 = ld8(gB1 + k0);
    __syncthreads();
    st8(&As[srow * 32 + skoff],        va0);
    st8(&As[(64 + srow) * 32 + skoff], va1);
    st8(&Bs[srow * 32 + skoff],        vb0);
    st8(&Bs[(64 + srow) * 32 + skoff], vb1);
    __syncthreads();

    frag8 a[4], b[4];
#pragma unroll
    for (int i = 0; i < 4; i++)
      a[i] = *(const frag8*)&As[(wr + i * 16 + arow) * 32 + akoff];
#pragma unroll
    for (int j = 0; j < 4; j++)
      b[j] = *(const frag8*)&Bs[(wc + j * 16 + arow) * 32 + akoff];
#pragma unroll
    for (int i = 0; i < 4; i++)
#pragma unroll
      for (int j = 0; j < 4; j++)
        acc[i][j] = __builtin_amdgcn_mfma_f32_16x16x32_bf16(a[i], b[j], acc[i][j], 0, 0, 0);
  }
#pragma unroll
  for (int i = 0; i < 4; i++)
#pragma unroll
    for (int j = 0; j < 4; j++) {
      const int col = bn + wc + j * 16 + (lane & 15);
      const float bv = bias[col];
#pragma unroll
      for (int r = 0; r < 4; r++) {
        const int row = bm + wr + i * 16 + (lane >> 4) * 4 + r;
        store_out(Y, (size_t)row * N + col, acc[i][j][r] + bv);
      }
    }
}

// ------- pre_fused_v4: 512 thr, 8 waves x 2 rows, LDS weight staging ---------
__global__ __launch_bounds__(512, 2)
void pre_fused_v4(const float* __restrict__ x,
                  const float* __restrict__ dw_w, const float* __restrict__ dw_b,
                  const float* __restrict__ ln_g, const float* __restrict__ ln_b,
                  const float* __restrict__ Wo,   const float* __restrict__ bo,
                  const float* __restrict__ Wm,   const float* __restrict__ bmb,
                  __hip_bfloat16* __restrict__ xbb,
                  float* __restrict__ coef)
{
  __shared__ float sW[16384];          // 64 KB: Wo[7168] | Wm[7168] | lng[1024] | lnb[1024]
  float* sWo  = sW;
  float* sWm  = sW + 7168;
  float* slng = sW + 14336;
  float* slnb = sW + 15360;

  const int tid  = threadIdx.x;        // 0..511
  const int lane = tid & 63;
  const int wid  = tid >> 6;           // 0..7

#pragma unroll
  for (int i = 0; i < 3; i++) {
    gl_lds16(Wo + (size_t)(i * 512 + tid) * 4, &sWo[(i * 512 + tid) * 4]);
    gl_lds16(Wm + (size_t)(i * 512 + tid) * 4, &sWm[(i * 512 + tid) * 4]);
  }
  if (tid < 256) {
    gl_lds16(Wo + (size_t)(1536 + tid) * 4, &sWo[(1536 + tid) * 4]);
    gl_lds16(Wm + (size_t)(1536 + tid) * 4, &sWm[(1536 + tid) * 4]);
    gl_lds16(ln_g + (size_t)tid * 4, &slng[tid * 4]);
  } else {
    const int t = tid - 256;
    gl_lds16(ln_b + (size_t)t * 4, &slnb[t * 4]);
  }
  __syncthreads();

  const int b    = blockIdx.x;               // 512 blocks
  const int bs   = (b & 7) * 64 + (b >> 3);  // XCD-contiguous row spans
  const int row0 = bs * 16 + wid * 2;        // wave's first row (2 consecutive)
  const int l0   = row0 & (L_DIM - 1);

  const float* xr = x + (size_t)row0 * C_DIM;

  float4 v[2][4];   // [row][chunk]
#pragma unroll
  for (int j = 0; j < 4; j++) {
    const int c4 = j * 256 + lane * 4;
    float4 xv[4];
#pragma unroll
    for (int m = 0; m < 4; m++) {
      const int lm = l0 + m - 1;
      if (lm >= 0 && lm < L_DIM)
        xv[m] = *(const float4*)(xr + ((long)m - 1) * C_DIM + c4);
      else
        xv[m] = make_float4(0.f, 0.f, 0.f, 0.f);
    }
#pragma unroll
    for (int r = 0; r < 2; r++)
      stbf4(xbb + (size_t)(row0 + r) * C_DIM + c4, xv[r + 1]);

    const float4 w0 = *(const float4*)(dw_w + (size_t)c4 * 3);
    const float4 w1 = *(const float4*)(dw_w + (size_t)c4 * 3 + 4);
    const float4 w2 = *(const float4*)(dw_w + (size_t)c4 * 3 + 8);
    const float4 bb = *(const float4*)(dw_b + c4);
#pragma unroll
    for (int r = 0; r < 2; r++) {
      const float4 xm = xv[r], x0 = xv[r + 1], xq = xv[r + 2];
      v[r][j].x = xm.x * w0.x + x0.x * w0.y + xq.x * w0.z + bb.x;
      v[r][j].y = xm.y * w0.w + x0.y * w1.x + xq.y * w1.y + bb.y;
      v[r][j].z = xm.z * w1.z + x0.z * w1.w + xq.z * w2.x + bb.z;
      v[r][j].w = xm.w * w2.y + x0.w * w2.z + xq.w * w2.w + bb.w;
    }
  }

  float mu[2], rstd[2];
#pragma unroll
  for (int r = 0; r < 2; r++) {
    float s1 = 0.f, s2 = 0.f;
#pragma unroll
    for (int j = 0; j < 4; j++) {
      s1 += v[r][j].x + v[r][j].y + v[r][j].z + v[r][j].w;
      s2 += v[r][j].x * v[r][j].x + v[r][j].y * v[r][j].y
          + v[r][j].z * v[r][j].z + v[r][j].w * v[r][j].w;
    }
    const float t1 = s1 + __shfl_xor(s1, 32);
    const float t2 = s2 + __shfl_xor(s2, 32);
    float cc = (lane < 32) ? t1 : t2;
#pragma unroll
    for (int m = 16; m >= 1; m >>= 1) cc += __shfl_xor(cc, m);
    const float dd = __shfl_xor(cc, 32);
    const float S1 = (lane < 32) ? cc : dd;
    const float S2 = (lane < 32) ? dd : cc;
    mu[r]   = S1 * (1.f / C_DIM);
    rstd[r] = rsqrtf(S2 * (1.f / C_DIM) - mu[r] * mu[r] + 1e-5f);
  }

  float po[2][7] = {}, pm[2][7] = {};
#pragma unroll
  for (int j = 0; j < 4; j++) {
    const int c4 = j * 256 + lane * 4;
    const float4 gg = *(const float4*)&slng[c4];
    const float4 bb = *(const float4*)&slnb[c4];
    float4 g[2];
#pragma unroll
    for (int r = 0; r < 2; r++) {
      g[r].x = gelu_fast((v[r][j].x - mu[r]) * rstd[r] * gg.x + bb.x);
      g[r].y = gelu_fast((v[r][j].y - mu[r]) * rstd[r] * gg.y + bb.y);
      g[r].z = gelu_fast((v[r][j].z - mu[r]) * rstd[r] * gg.z + bb.z);
      g[r].w = gelu_fast((v[r][j].w - mu[r]) * rstd[r] * gg.w + bb.w);
    }
#pragma unroll
    for (int k = 0; k < 7; k++) {
      const float4 wo = *(const float4*)&sWo[k * 1024 + c4];
      const float4 wm = *(const float4*)&sWm[k * 1024 + c4];
#pragma unroll
      for (int r = 0; r < 2; r++) {
        po[r][k] += g[r].x * wo.x + g[r].y * wo.y + g[r].z * wo.z + g[r].w * wo.w;
        pm[r][k] += g[r].x * wm.x + g[r].y * wm.y + g[r].z * wm.z + g[r].w * wm.w;
      }
    }
  }

  float poS[2][7], pmS[2][7];
#pragma unroll
  for (int r = 0; r < 2; r++)
#pragma unroll
    for (int k = 0; k < 7; k++) {
      const float tp = po[r][k] + __shfl_xor(po[r][k], 32);
      const float tm = pm[r][k] + __shfl_xor(pm[r][k], 32);
      float cc = (lane < 32) ? tp : tm;
#pragma unroll
      for (int m = 16; m >= 1; m >>= 1) cc += __shfl_xor(cc, m);
      const float dd = __shfl_xor(cc, 32);
      poS[r][k] = (lane < 32) ? cc : dd;
      pmS[r][k] = (lane < 32) ? dd : cc;
    }

#pragma unroll
  for (int r = 0; r < 2; r++) {
    float lg[7], mx = -1e30f;
#pragma unroll
    for (int k = 0; k < 7; k++) { lg[k] = pmS[r][k] + bmb[k]; mx = fmaxf(mx, lg[k]); }
    float se = 0.f, e[7];
#pragma unroll
    for (int k = 0; k < 7; k++) { e[k] = __expf(lg[k] - mx); se += e[k]; }
    const float inv = 1.f / se;
    const int l = l0 + r;

    if (lane == r) {
      float pk[32];
#pragma unroll
      for (int k = 0; k < 7; k++) {
        const float msk = e[k] * inv;
        const float off = (poS[r][k] + bo[k]) * 2.0f;
        const float ap  = (float)l + (float)(k - 3) + off;
        const float apc = fminf(fmaxf(ap, 0.f), (float)(L_DIM - 1));
        int f = (int)apc;
        int c = f + 1; if (c > L_DIM - 1) c = L_DIM - 1;
        const float w1  = apc - (float)f;
        const float val = (ap < 0.f || ap > (float)(L_DIM - 1)) ? 0.f : 1.f;
        pk[k]      = (1.f - w1) * val * msk;   // wf (mask folded in)
        pk[8 + k]  = w1 * val * msk;           // wc
        pk[16 + k] = (float)f;                 // pf
        pk[24 + k] = (float)c;                 // pc
      }
      pk[7] = pk[15] = pk[23] = pk[31] = 0.f;
      float* cr = coef + (size_t)(row0 + r) * 32;
#pragma unroll
      for (int q = 0; q < 8; q++)
        *(float4*)(cr + q * 4) = make_float4(pk[q*4], pk[q*4+1], pk[q*4+2], pk[q*4+3]);
    }
  }
}

// ------- gather_g: coef + xbb -> g (bf16) and s=SUM(w) per row ---------------
__global__ __launch_bounds__(256)
void gather_g(const float* __restrict__ coef,
              const __hip_bfloat16* __restrict__ xbb,
              __hip_bfloat16* __restrict__ gb,
              float* __restrict__ sArr)
{
  const int b    = blockIdx.x;                 // 2048 blocks
  const int bs   = (b & 7) * 256 + (b >> 3);   // XCD-contiguous row spans
  const int wid  = threadIdx.x >> 6;
  const int lane = threadIdx.x & 63;
  const int row  = bs * 4 + wid;
  const int n    = row >> 11;

  const float* cr = coef + (size_t)row * 32;
  const float4 q0 = *(const float4*)(cr);       // wf 0..3
  const float4 q1 = *(const float4*)(cr + 4);   // wf 4..6
  const float4 q2 = *(const float4*)(cr + 8);   // wc 0..3
  const float4 q3 = *(const float4*)(cr + 12);  // wc 4..6
  const float4 q4 = *(const float4*)(cr + 16);  // pf 0..3
  const float4 q5 = *(const float4*)(cr + 20);  // pf 4..6
  const float4 q6 = *(const float4*)(cr + 24);  // pc 0..3
  const float4 q7 = *(const float4*)(cr + 28);  // pc 4..6

  const float wf[7] = {q0.x, q0.y, q0.z, q0.w, q1.x, q1.y, q1.z};
  const float wc[7] = {q2.x, q2.y, q2.z, q2.w, q3.x, q3.y, q3.z};
  const int   pf[7] = {(int)q4.x, (int)q4.y, (int)q4.z, (int)q4.w, (int)q5.x, (int)q5.y, (int)q5.z};
  const int   pc[7] = {(int)q6.x, (int)q6.y, (int)q6.z, (int)q6.w, (int)q7.x, (int)q7.y, (int)q7.z};

  if (lane == 0) {   // s = sum of all blend weights (for the s*(Wout@bi) term)
    sArr[row] = q0.x + q0.y + q0.z + q0.w + q1.x + q1.y + q1.z
              + q2.x + q2.y + q2.z + q2.w + q3.x + q3.y + q3.z;
  }

  const __hip_bfloat16* xpn = xbb + ((size_t)n * L_DIM) * C_DIM;
  __hip_bfloat16* so = gb + (size_t)row * C_DIM;

#pragma unroll
  for (int j = 0; j < 2; j++) {
    const int c8 = j * 512 + lane * 8;
    float a[8] = {0.f, 0.f, 0.f, 0.f, 0.f, 0.f, 0.f, 0.f};
#pragma unroll
    for (int k = 0; k < 7; k++) {
      union { int4 q; __hip_bfloat16 h[8]; } uf, uc;
      uf.q = *(const int4*)(xpn + (size_t)pf[k] * C_DIM + c8);
      uc.q = *(const int4*)(xpn + (size_t)pc[k] * C_DIM + c8);
#pragma unroll
      for (int t = 0; t < 8; t++)
        a[t] += wf[k] * (float)uf.h[t] + wc[k] * (float)uc.h[t];
    }
    union { int4 q; __hip_bfloat16 h[8]; } uo;
#pragma unroll
    for (int t = 0; t < 8; t++) uo.h[t] = __float2bfloat16(a[t]);
    *(int4*)(so + c8) = uo.q;
  }
}

// ------- mid v4 kept for small-workspace fallback paths -------
__global__ __launch_bounds__(256)
void mid_fused_v4(const float* __restrict__ x,
                  const float* __restrict__ dw_w, const float* __restrict__ dw_b,
                  const float* __restrict__ ln_g, const float* __restrict__ ln_b,
                  const float* __restrict__ Wo,   const float* __restrict__ bo,
                  const float* __restrict__ Wm,   const float* __restrict__ bmb,
                  const __hip_bfloat16* __restrict__ xp,
                  __hip_bfloat16* __restrict__ smp)
{
  const int b    = blockIdx.x;
  const int bs   = (b & 7) * 256 + (b >> 3);
  const int wid  = threadIdx.x >> 6;
  const int lane = threadIdx.x & 63;
  const int row  = bs * 4 + wid;
  const int l    = row & (L_DIM - 1);
  const int n    = row >> 11;

  const float* xr = x + (size_t)row * C_DIM;

  float4 v[4];
#pragma unroll
  for (int j = 0; j < 4; j++) {
    const int c4 = j * 256 + lane * 4;
    const float4 x0 = *(const float4*)(xr + c4);
    float4 xm = make_float4(0.f, 0.f, 0.f, 0.f);
    float4 xq = make_float4(0.f, 0.f, 0.f, 0.f);
    if (l > 0)         xm = *(const float4*)(xr + c4 - C_DIM);
    if (l < L_DIM - 1) xq = *(const float4*)(xr + c4 + C_DIM);
    const float4 w0 = *(const float4*)(dw_w + (size_t)c4 * 3);
    const float4 w1 = *(const float4*)(dw_w + (size_t)c4 * 3 + 4);
    const float4 w2 = *(const float4*)(dw_w + (size_t)c4 * 3 + 8);
    const float4 bb = *(const float4*)(dw_b + c4);
    v[j].x = xm.x * w0.x + x0.x * w0.y + xq.x * w0.z + bb.x;
    v[j].y = xm.y * w0.w + x0.y * w1.x + xq.y * w1.y + bb.y;
    v[j].z = xm.z * w1.z + x0.z * w1.w + xq.z * w2.x + bb.z;
    v[j].w = xm.w * w2.y + x0.w * w2.z + xq.w * w2.w + bb.w;
  }

  float s1 = 0.f, s2 = 0.f;
#pragma unroll
  for (int j = 0; j < 4; j++) {
    s1 += v[j].x + v[j].y + v[j].z + v[j].w;
    s2 += v[j].x * v[j].x + v[j].y * v[j].y + v[j].z * v[j].z + v[j].w * v[j].w;
  }
#pragma unroll
  for (int m = 1; m < 64; m <<= 1) { s1 += __shfl_xor(s1, m); s2 += __shfl_xor(s2, m); }
  const float mu   = s1 * (1.f / C_DIM);
  const float rstd = rsqrtf(s2 * (1.f / C_DIM) - mu * mu + 1e-5f);

  float4 g[4];
#pragma unroll
  for (int j = 0; j < 4; j++) {
    const int c4 = j * 256 + lane * 4;
    const float4 gg = *(const float4*)(ln_g + c4);
    const float4 bb = *(const float4*)(ln_b + c4);
    g[j].x = gelu_fast((v[j].x - mu) * rstd * gg.x + bb.x);
    g[j].y = gelu_fast((v[j].y - mu) * rstd * gg.y + bb.y);
    g[j].z = gelu_fast((v[j].z - mu) * rstd * gg.z + bb.z);
    g[j].w = gelu_fast((v[j].w - mu) * rstd * gg.w + bb.w);
  }

  float po[7] = {0,0,0,0,0,0,0}, pm[7] = {0,0,0,0,0,0,0};
#pragma unroll
  for (int k = 0; k < 7; k++) {
#pragma unroll
    for (int j = 0; j < 4; j++) {
      const int c4 = j * 256 + lane * 4;
      const float4 wo = *(const float4*)(Wo + (size_t)k * C_DIM + c4);
      const float4 wm = *(const float4*)(Wm + (size_t)k * C_DIM + c4);
      po[k] += g[j].x * wo.x + g[j].y * wo.y + g[j].z * wo.z + g[j].w * wo.w;
      pm[k] += g[j].x * wm.x + g[j].y * wm.y + g[j].z * wm.z + g[j].w * wm.w;
    }
  }
#pragma unroll
  for (int k = 0; k < 7; k++)
#pragma unroll
    for (int m = 1; m < 64; m <<= 1) {
      po[k] += __shfl_xor(po[k], m);
      pm[k] += __shfl_xor(pm[k], m);
    }

  float lg[7], mx = -1e30f;
#pragma unroll
  for (int k = 0; k < 7; k++) { lg[k] = pm[k] + bmb[k]; mx = fmaxf(mx, lg[k]); }
  float se = 0.f, e[7];
#pragma unroll
  for (int k = 0; k < 7; k++) { e[k] = __expf(lg[k] - mx); se += e[k]; }
  const float inv = 1.f / se;

  float wf[7], wcl[7]; int pf[7], pc[7];
#pragma unroll
  for (int k = 0; k < 7; k++) {
    const float msk = e[k] * inv;
    const float off = (po[k] + bo[k]) * 2.0f;
    const float ap  = (float)l + (float)(k - 3) + off;
    const float apc = fminf(fmaxf(ap, 0.f), (float)(L_DIM - 1));
    int f = (int)apc;
    int c = f + 1; if (c > L_DIM - 1) c = L_DIM - 1;
    const float w1  = apc - (float)f;
    const float val = (ap < 0.f || ap > (float)(L_DIM - 1)) ? 0.f : 1.f;
    wf[k]  = (1.f - w1) * val * msk;
    wcl[k] = w1 * val * msk;
    pf[k] = f; pc[k] = c;
  }

  const __hip_bfloat16* xpn = xp + ((size_t)n * L_DIM) * C_DIM;
  __hip_bfloat16* so = smp + (size_t)row * C_DIM;
#pragma unroll
  for (int j = 0; j < 4; j++) {
    const int c4 = j * 256 + lane * 4;
    float4 a = make_float4(0.f, 0.f, 0.f, 0.f);
#pragma unroll
    for (int k = 0; k < 7; k++) {
      const float4 vf = ldbf4(xpn + (size_t)pf[k] * C_DIM + c4);
      const float4 vc = ldbf4(xpn + (size_t)pc[k] * C_DIM + c4);
      a.x += wf[k] * vf.x + wcl[k] * vc.x;
      a.y += wf[k] * vf.y + wcl[k] * vc.y;
      a.z += wf[k] * vf.z + wcl[k] * vc.z;
      a.w += wf[k] * vf.w + wcl[k] * vc.w;
    }
    stbf4(so + c4, a);
  }
}

// ---------------- host ----------------
extern "C" void kernel_launch(void* const* d_in, const int* in_sizes, int n_in,
                              void* d_out, int out_size, void* d_ws, size_t ws_size,
                              hipStream_t stream)
{
  const float* x    = (const float*)d_in[0];
  const float* Wi   = (const float*)d_in[1];
  const float* bi   = (const float*)d_in[2];
  const float* dw_w = (const float*)d_in[3];
  const float* dw_b = (const float*)d_in[4];
  const float* ln_g = (const float*)d_in[5];
  const float* ln_b = (const float*)d_in[6];
  const float* Wo   = (const float*)d_in[7];
  const float* bo   = (const float*)d_in[8];
  const float* Wm   = (const float*)d_in[9];
  const float* bm   = (const float*)d_in[10];
  const float* Wout = (const float*)d_in[11];
  const float* bout = (const float*)d_in[12];
  float* out = (float*)d_out;

  const size_t XE = (size_t)M_DIM * C_DIM;
  const size_t WE = (size_t)C_DIM * C_DIM;
  char* wsb = (char*)d_ws;

  // ---- new collapsed-GEMM path layout ----
  __hip_bfloat16* xbb2  = (__hip_bfloat16*)wsb;                       // XE*2
  __hip_bfloat16* gb    = (__hip_bfloat16*)(wsb + XE * 2);            // XE*2
  __hip_bfloat16* Woutb2= (__hip_bfloat16*)(wsb + XE * 4);            // WE*2
  __hip_bfloat16* WiT   = (__hip_bfloat16*)(wsb + XE * 4 + WE * 2);   // WE*2
  __hip_bfloat16* Wcb   = (__hip_bfloat16*)(wsb + XE * 4 + WE * 4);   // WE*2
  float* coef2 = (float*)(wsb + XE * 4 + WE * 6);                     // M*128
  float* sArr  = (float*)(wsb + XE * 4 + WE * 6 + (size_t)M_DIM * 128);
  float* bvec  = (float*)(wsb + XE * 4 + WE * 6 + (size_t)M_DIM * 128 + (size_t)M_DIM * 4);
  const size_t need_v5 = XE * 4 + WE * 6 + (size_t)M_DIM * 132 + 4096;

  // ---- legacy layouts (fallbacks) ----
  __hip_bfloat16* xp    = (__hip_bfloat16*)wsb;
  __hip_bfloat16* smp   = (__hip_bfloat16*)(wsb + XE * 2);
  __hip_bfloat16* Wib   = (__hip_bfloat16*)(wsb + XE * 4);
  __hip_bfloat16* Woutb = (__hip_bfloat16*)(wsb + XE * 4 + WE * 2);
  __hip_bfloat16* xbb   = (__hip_bfloat16*)(wsb + XE * 4 + WE * 4);
  const size_t need_w2   = XE * 4 + WE * 4;
  const size_t need_full = need_w2 + XE * 2;

  dim3 gg(M_DIM / 128, C_DIM / 128);   // 64 x 8

  if (ws_size >= need_v5) {
    // collapsed pipeline:
    //   W_comb = Wout@Wi (bf16), bvec = Wout@bi
    //   g = SUM_k w_k * x[p_k]  (gather on x, commutes with the linear proj)
    //   out = g @ W_comb^T + s*bvec + bout
    cvt_trans_wi<<<dim3(16, 16), 256, 0, stream>>>(Wi, WiT);
    cvt_wout_bvec<<<768, 256, 0, stream>>>(Wout, Woutb2, bi, bvec);
    gemm_db<__hip_bfloat16><<<dim3(8, 8), 256, 0, stream>>>(
        Woutb2, WiT, nullptr, Wcb, C_DIM, C_DIM, C_DIM, nullptr, nullptr);
    pre_fused_v4<<<M_DIM / 16, 512, 0, stream>>>(
        x, dw_w, dw_b, ln_g, ln_b, Wo, bo, Wm, bm, xbb2, coef2);
    gather_g<<<M_DIM / 4, 256, 0, stream>>>(coef2, xbb2, gb, sArr);
    gemm_db<float><<<gg, 256, 0, stream>>>(
        gb, Wcb, bout, out, M_DIM, C_DIM, C_DIM, sArr, bvec);
  } else if (ws_size >= need_full) {
    cvt_f32_bf16<<<(int)(XE / 8 / 256), 256, 0, stream>>>(x, xbb, (int)(XE / 8));
    cvt_two_f32_bf16<<<(int)(2 * (WE / 8) / 256), 256, 0, stream>>>(
        Wi, Wib, Wout, Woutb, (int)(WE / 8));
    gemm_db<__hip_bfloat16><<<gg, 256, 0, stream>>>(xbb, Wib, bi, xp, M_DIM, C_DIM, C_DIM,
                                                    nullptr, nullptr);
    mid_fused_v4<<<M_DIM / 4, 256, 0, stream>>>(x, dw_w, dw_b, ln_g, ln_b, Wo, bo, Wm, bm, xp, smp);
    gemm_db<float><<<gg, 256, 0, stream>>>(smp, Woutb, bout, out, M_DIM, C_DIM, C_DIM,
                                           nullptr, nullptr);
  } else if (ws_size >= need_w2) {
    cvt_f32_bf16<<<(int)(WE / 8 / 256), 256, 0, stream>>>(Wout, Woutb, (int)(WE / 8));
    gemm_nt<float, __hip_bfloat16><<<gg, 256, 0, stream>>>(x, Wi, bi, xp, M_DIM, C_DIM, C_DIM);
    mid_fused_v4<<<M_DIM / 4, 256, 0, stream>>>(x, dw_w, dw_b, ln_g, ln_b, Wo, bo, Wm, bm, xp, smp);
    gemm_db<float><<<gg, 256, 0, stream>>>(smp, Woutb, bout, out, M_DIM, C_DIM, C_DIM,
                                           nullptr, nullptr);
  } else {
    gemm_nt<float, __hip_bfloat16><<<gg, 256, 0, stream>>>(x, Wi, bi, xp, M_DIM, C_DIM, C_DIM);
    mid_fused_v4<<<M_DIM / 4, 256, 0, stream>>>(x, dw_w, dw_b, ln_g, ln_b, Wo, bo, Wm, bm, xp, smp);
    gemm_nt<__hip_bfloat16, float><<<gg, 256, 0, stream>>>(smp, Wout, bout, out, M_DIM, C_DIM, C_DIM);
  }
}

// Round 6
// 185.261 us; speedup vs baseline: 1.0898x; 1.0898x over previous
//
#include <hip/hip_runtime.h>
#include <hip/hip_bf16.h>
#include <cstdint>

#define C_DIM 1024
#define L_DIM 2048
#define N_DIM 4
#define M_DIM (N_DIM * L_DIM)   // 8192

typedef __attribute__((ext_vector_type(8))) short frag8;    // 8 bf16 = 4 VGPRs
typedef __attribute__((ext_vector_type(4)))  float f32x4;
typedef __attribute__((ext_vector_type(16))) float f32x16;

// ---------------- helpers ----------------
__device__ __forceinline__ void gl_lds16(const void* g, void* l) {
  __builtin_amdgcn_global_load_lds((const __attribute__((address_space(1))) void*)g,
                                   (__attribute__((address_space(3))) void*)l,
                                   16, 0, 0);
}
__device__ __forceinline__ void store_out(float* Y, size_t idx, float v) { Y[idx] = v; }
__device__ __forceinline__ void store_out(__hip_bfloat16* Y, size_t idx, float v) {
  Y[idx] = __float2bfloat16(v);
}
__device__ __forceinline__ float4 ldbf4(const __hip_bfloat16* p) {
  union { short4 s; __hip_bfloat16 h[4]; } u; u.s = *(const short4*)p;
  return make_float4((float)u.h[0], (float)u.h[1], (float)u.h[2], (float)u.h[3]);
}
__device__ __forceinline__ void stbf4(__hip_bfloat16* p, float4 v) {
  union { short4 s; __hip_bfloat16 h[4]; } u;
  u.h[0] = __float2bfloat16(v.x); u.h[1] = __float2bfloat16(v.y);
  u.h[2] = __float2bfloat16(v.z); u.h[3] = __float2bfloat16(v.w);
  *(short4*)p = u.s;
}
// fast GELU (tanh form)
__device__ __forceinline__ float gelu_fast(float t) {
  const float t3 = t * t * t;
  const float ns = -1.5957691216f * t - 0.0713548163f * t3;
  return t / (1.f + __expf(ns));
}

// fp32 -> bf16 bulk convert, 8 elems/thread (fallback paths)
__global__ __launch_bounds__(256)
void cvt_f32_bf16(const float* __restrict__ in, __hip_bfloat16* __restrict__ out, int n8) {
  const int i = blockIdx.x * 256 + threadIdx.x;
  if (i >= n8) return;
  const float4 a = *(const float4*)(in + (size_t)i * 8);
  const float4 b = *(const float4*)(in + (size_t)i * 8 + 4);
  union { __hip_bfloat16 h[8]; int4 q; } u;
  u.h[0] = __float2bfloat16(a.x); u.h[1] = __float2bfloat16(a.y);
  u.h[2] = __float2bfloat16(a.z); u.h[3] = __float2bfloat16(a.w);
  u.h[4] = __float2bfloat16(b.x); u.h[5] = __float2bfloat16(b.y);
  u.h[6] = __float2bfloat16(b.z); u.h[7] = __float2bfloat16(b.w);
  *(int4*)(out + (size_t)i * 8) = u.q;
}

__global__ __launch_bounds__(256)
void cvt_two_f32_bf16(const float* __restrict__ inA, __hip_bfloat16* __restrict__ outA,
                      const float* __restrict__ inB, __hip_bfloat16* __restrict__ outB,
                      int n8each) {
  int i = blockIdx.x * 256 + threadIdx.x;
  const float* in; __hip_bfloat16* out;
  if (i < n8each) { in = inA; out = outA; }
  else            { in = inB; out = outB; i -= n8each; }
  if (i >= n8each) return;
  const float4 a = *(const float4*)(in + (size_t)i * 8);
  const float4 b = *(const float4*)(in + (size_t)i * 8 + 4);
  union { __hip_bfloat16 h[8]; int4 q; } u;
  u.h[0] = __float2bfloat16(a.x); u.h[1] = __float2bfloat16(a.y);
  u.h[2] = __float2bfloat16(a.z); u.h[3] = __float2bfloat16(a.w);
  u.h[4] = __float2bfloat16(b.x); u.h[5] = __float2bfloat16(b.y);
  u.h[6] = __float2bfloat16(b.z); u.h[7] = __float2bfloat16(b.w);
  *(int4*)(out + (size_t)i * 8) = u.q;
}

// ------- GEMM: BK=64, double-buffered LDS, 32x32x16 MFMA, 1 barrier/iter -------
// Y[M,N] = X[M,K] @ W[N,K]^T (+ bias[col]) (+ sArr[row]*bvec[col]).
template <typename TY>
__global__ __launch_bounds__(256, 2)
void gemm_db(const __hip_bfloat16* __restrict__ X,
             const __hip_bfloat16* __restrict__ W,
             const float* __restrict__ bias,
             TY* __restrict__ Y, int M, int N, int K,
             const float* __restrict__ sArr, const float* __restrict__ bvec)
{
  __shared__ __hip_bfloat16 As[2][2][128 * 32];   // [buf][panel]
  __shared__ __hip_bfloat16 Bs[2][2][128 * 32];
  const int tid  = threadIdx.x;
  const int lane = tid & 63;
  const int wave = tid >> 6;
  const int bm = blockIdx.x * 128;
  const int bn = blockIdx.y * 128;
  const int wr = (wave >> 1) * 64;
  const int wc = (wave & 1) * 64;
  const int srow  = tid >> 2;       // 0..63
  const int skoff = (tid & 3) * 8;  // elements

  const __hip_bfloat16* gA0 = X + (size_t)(bm + srow) * K + skoff;
  const __hip_bfloat16* gA1 = X + (size_t)(bm + 64 + srow) * K + skoff;
  const __hip_bfloat16* gB0 = W + (size_t)(bn + srow) * K + skoff;
  const __hip_bfloat16* gB1 = W + (size_t)(bn + 64 + srow) * K + skoff;

  f32x16 acc[2][2] = {};
  const int arow  = lane & 31;
  const int akoff = (lane >> 5) * 8;

#define STAGE(k0, buf)                                        \
  do {                                                        \
    gl_lds16(gA0 + (k0),      &As[buf][0][tid * 8]);          \
    gl_lds16(gA1 + (k0),      &As[buf][0][2048 + tid * 8]);   \
    gl_lds16(gA0 + (k0) + 32, &As[buf][1][tid * 8]);          \
    gl_lds16(gA1 + (k0) + 32, &As[buf][1][2048 + tid * 8]);   \
    gl_lds16(gB0 + (k0),      &Bs[buf][0][tid * 8]);          \
    gl_lds16(gB1 + (k0),      &Bs[buf][0][2048 + tid * 8]);   \
    gl_lds16(gB0 + (k0) + 32, &Bs[buf][1][tid * 8]);          \
    gl_lds16(gB1 + (k0) + 32, &Bs[buf][1][2048 + tid * 8]);   \
  } while (0)

  STAGE(0, 0);
  __syncthreads();
  const int iters = K / 64;
  for (int it = 0; it < iters; ++it) {
    const int cur = it & 1;
    if (it + 1 < iters) STAGE((it + 1) * 64, cur ^ 1);   // prefetch next tile

#pragma unroll
    for (int p = 0; p < 2; ++p)
#pragma unroll
      for (int h = 0; h < 2; ++h) {
        const frag8 a0 = *(const frag8*)&As[cur][p][(wr + arow) * 32 + h * 16 + akoff];
        const frag8 a1 = *(const frag8*)&As[cur][p][(wr + 32 + arow) * 32 + h * 16 + akoff];
        const frag8 b0 = *(const frag8*)&Bs[cur][p][(wc + arow) * 32 + h * 16 + akoff];
        const frag8 b1 = *(const frag8*)&Bs[cur][p][(wc + 32 + arow) * 32 + h * 16 + akoff];
        acc[0][0] = __builtin_amdgcn_mfma_f32_32x32x16_bf16(a0, b0, acc[0][0], 0, 0, 0);
        acc[0][1] = __builtin_amdgcn_mfma_f32_32x32x16_bf16(a0, b1, acc[0][1], 0, 0, 0);
        acc[1][0] = __builtin_amdgcn_mfma_f32_32x32x16_bf16(a1, b0, acc[1][0], 0, 0, 0);
        acc[1][1] = __builtin_amdgcn_mfma_f32_32x32x16_bf16(a1, b1, acc[1][1], 0, 0, 0);
      }
    __syncthreads();   // drains prefetch loads + protects buf reuse
  }
#undef STAGE

  // C/D layout (32x32): col=lane&31, row=(r&3)+8*(r>>2)+4*(lane>>5)  [m74/m101]
#pragma unroll
  for (int i = 0; i < 2; i++)
#pragma unroll
    for (int j = 0; j < 2; j++) {
      const int col = bn + wc + j * 32 + (lane & 31);
      const float bv  = bias ? bias[col] : 0.f;
      const float bvv = (sArr && bvec) ? bvec[col] : 0.f;
#pragma unroll
      for (int r = 0; r < 16; r++) {
        const int row = bm + wr + i * 32 + (r & 3) + 8 * (r >> 2) + 4 * (lane >> 5);
        float extra = bv;
        if (sArr) extra += sArr[row] * bvv;
        store_out(Y, (size_t)row * N + col, acc[i][j][r] + extra);
      }
    }
}

// ---------------- fallback GEMM (16x16, register staging) ----------------
struct Ld8f { float4 a, b; };
struct Ld8b { int4 a; };
__device__ __forceinline__ Ld8f ld8(const float* p) {
  return { *(const float4*)p, *(const float4*)(p + 4) };
}
__device__ __forceinline__ Ld8b ld8(const __hip_bfloat16* p) { return { *(const int4*)p }; }
__device__ __forceinline__ void st8(__hip_bfloat16* l, const Ld8f& v) {
  union { __hip_bfloat16 h[8]; int4 q; } u;
  u.h[0] = __float2bfloat16(v.a.x); u.h[1] = __float2bfloat16(v.a.y);
  u.h[2] = __float2bfloat16(v.a.z); u.h[3] = __float2bfloat16(v.a.w);
  u.h[4] = __float2bfloat16(v.b.x); u.h[5] = __float2bfloat16(v.b.y);
  u.h[6] = __float2bfloat16(v.b.z); u.h[7] = __float2bfloat16(v.b.w);
  *(int4*)l = u.q;
}
__device__ __forceinline__ void st8(__hip_bfloat16* l, const Ld8b& v) { *(int4*)l = v.a; }

template <typename TX, typename TY>
__global__ __launch_bounds__(256, 2)
void gemm_nt(const TX* __restrict__ X, const float* __restrict__ W,
             const float* __restrict__ bias, TY* __restrict__ Y, int M, int N, int K)
{
  __shared__ __hip_bfloat16 As[128 * 32];
  __shared__ __hip_bfloat16 Bs[128 * 32];
  const int tid  = threadIdx.x;
  const int lane = tid & 63;
  const int wave = tid >> 6;
  const int bm = blockIdx.x * 128;
  const int bn = blockIdx.y * 128;
  const int wr = (wave >> 1) * 64;
  const int wc = (wave & 1) * 64;
  const int srow  = tid >> 2;
  const int skoff = (tid & 3) * 8;

  f32x4 acc[4][4] = {};
  const TX*    gA0 = X + (size_t)(bm + srow) * K + skoff;
  const TX*    gA1 = X + (size_t)(bm + 64 + srow) * K + skoff;
  const float* gB0 = W + (size_t)(bn + srow) * K + skoff;
  const float* gB1 = W + (size_t)(bn + 64 + srow) * K + skoff;
  const int arow  = lane & 15;
  const int akoff = (lane >> 4) * 8;

  for (int k0 = 0; k0 < K; k0 += 32) {
    const auto va0 = ld8(gA0 + k0);
    const auto va1 = ld8(gA1 + k0);
    const auto vb0 = ld8(gB0 + k0);
    const auto vb1 = ld8(gB1 + k0);
    __syncthreads();
    st8(&As[srow * 32 + skoff],        va0);
    st8(&As[(64 + srow) * 32 + skoff], va1);
    st8(&Bs[srow * 32 + skoff],        vb0);
    st8(&Bs[(64 + srow) * 32 + skoff], vb1);
    __syncthreads();

    frag8 a[4], b[4];
#pragma unroll
    for (int i = 0; i < 4; i++)
      a[i] = *(const frag8*)&As[(wr + i * 16 + arow) * 32 + akoff];
#pragma unroll
    for (int j = 0; j < 4; j++)
      b[j] = *(const frag8*)&Bs[(wc + j * 16 + arow) * 32 + akoff];
#pragma unroll
    for (int i = 0; i < 4; i++)
#pragma unroll
      for (int j = 0; j < 4; j++)
        acc[i][j] = __builtin_amdgcn_mfma_f32_16x16x32_bf16(a[i], b[j], acc[i][j], 0, 0, 0);
  }
#pragma unroll
  for (int i = 0; i < 4; i++)
#pragma unroll
    for (int j = 0; j < 4; j++) {
      const int col = bn + wc + j * 16 + (lane & 15);
      const float bv = bias[col];
#pragma unroll
      for (int r = 0; r < 4; r++) {
        const int row = bm + wr + i * 16 + (lane >> 4) * 4 + r;
        store_out(Y, (size_t)row * N + col, acc[i][j][r] + bv);
      }
    }
}

// ====== L1: fused prep =======================================================
// blocks 0..511    : pre_fused_v4 body (x -> xbb bf16 copy + coef table)
// blocks 512..767  : Wi f32 -> WiT bf16 transpose (64x64 LDS tiles)
// blocks 768..1023 : Wout f32 -> bf16
// blocks 1024..1039: bvec = Wout @ bi
// All four jobs are mutually independent -> one launch.
__global__ __launch_bounds__(512, 2)
void fused_pre_prep(const float* __restrict__ x,
                    const float* __restrict__ dw_w, const float* __restrict__ dw_b,
                    const float* __restrict__ ln_g, const float* __restrict__ ln_b,
                    const float* __restrict__ Wo,   const float* __restrict__ bo,
                    const float* __restrict__ Wm,   const float* __restrict__ bmb,
                    const float* __restrict__ Wi,   const float* __restrict__ Wout,
                    const float* __restrict__ bi,
                    __hip_bfloat16* __restrict__ xbb,
                    float* __restrict__ coef,
                    __hip_bfloat16* __restrict__ WiT,
                    __hip_bfloat16* __restrict__ Woutb,
                    float* __restrict__ bvec)
{
  __shared__ float smem[16384];        // 64 KB, shared by block-type branches
  const int blk  = blockIdx.x;
  const int tid  = threadIdx.x;        // 0..511
  const int lane = tid & 63;
  const int wid  = tid >> 6;           // 0..7

  if (blk >= 1024) {                   // ---- bvec = Wout @ bi ----
    const int vb = blk - 1024;         // 0..15
#pragma unroll
    for (int rr = 0; rr < 8; rr++) {
      const int row = vb * 64 + wid * 8 + rr;
      const float* wr_ = Wout + (size_t)row * C_DIM;
      float s = 0.f;
#pragma unroll
      for (int c = 0; c < 4; c++) {
        const int j = c * 256 + lane * 4;
        const float4 w  = *(const float4*)(wr_ + j);
        const float4 bb = *(const float4*)(bi + j);
        s += w.x * bb.x + w.y * bb.y + w.z * bb.z + w.w * bb.w;
      }
#pragma unroll
      for (int m = 1; m < 64; m <<= 1) s += __shfl_xor(s, m);
      if (lane == 0) bvec[row] = s;
    }
    return;
  }
  if (blk >= 768) {                    // ---- Wout -> bf16 ----
    const int idx = (blk - 768) * 512 + tid;   // 8 elems each, 256*512*8 = WE
    const float4 a = *(const float4*)(Wout + (size_t)idx * 8);
    const float4 c = *(const float4*)(Wout + (size_t)idx * 8 + 4);
    union { __hip_bfloat16 h[8]; int4 q; } u;
    u.h[0] = __float2bfloat16(a.x); u.h[1] = __float2bfloat16(a.y);
    u.h[2] = __float2bfloat16(a.z); u.h[3] = __float2bfloat16(a.w);
    u.h[4] = __float2bfloat16(c.x); u.h[5] = __float2bfloat16(c.y);
    u.h[6] = __float2bfloat16(c.z); u.h[7] = __float2bfloat16(c.w);
    *(int4*)(Woutb + (size_t)idx * 8) = u.q;
    return;
  }
  if (blk >= 512) {                    // ---- Wi transpose -> WiT bf16 ----
    float (*tile)[65] = (float(*)[65])smem;    // 64x65 = 16.6 KB
    const int tb  = blk - 512;         // 0..255
    const int bi_ = tb >> 4;           // j-block
    const int bj  = tb & 15;           // k-block
    const int r   = tid >> 3;          // 0..63
    const int c0  = (tid & 7) * 8;     // 0..56
    const float* src = Wi + (size_t)(bi_ * 64 + r) * C_DIM + bj * 64 + c0;
    *(float4*)&tile[r][c0]     = *(const float4*)(src);
    *(float4*)&tile[r][c0 + 4] = *(const float4*)(src + 4);
    __syncthreads();
    union { __hip_bfloat16 h[8]; int4 q; } u;
#pragma unroll
    for (int i = 0; i < 8; i++) u.h[i] = __float2bfloat16(tile[c0 + i][r]);
    *(int4*)(WiT + (size_t)(bj * 64 + r) * C_DIM + bi_ * 64 + c0) = u.q;
    return;
  }

  // ---- pre_fused_v4 body (blocks 0..511) ----
  float* sWo  = smem;
  float* sWm  = smem + 7168;
  float* slng = smem + 14336;
  float* slnb = smem + 15360;

#pragma unroll
  for (int i = 0; i < 3; i++) {
    gl_lds16(Wo + (size_t)(i * 512 + tid) * 4, &sWo[(i * 512 + tid) * 4]);
    gl_lds16(Wm + (size_t)(i * 512 + tid) * 4, &sWm[(i * 512 + tid) * 4]);
  }
  if (tid < 256) {
    gl_lds16(Wo + (size_t)(1536 + tid) * 4, &sWo[(1536 + tid) * 4]);
    gl_lds16(Wm + (size_t)(1536 + tid) * 4, &sWm[(1536 + tid) * 4]);
    gl_lds16(ln_g + (size_t)tid * 4, &slng[tid * 4]);
  } else {
    const int t = tid - 256;
    gl_lds16(ln_b + (size_t)t * 4, &slnb[t * 4]);
  }
  __syncthreads();

  const int bs   = (blk & 7) * 64 + (blk >> 3);  // XCD-contiguous row spans
  const int row0 = bs * 16 + wid * 2;
  const int l0   = row0 & (L_DIM - 1);
  const float* xr = x + (size_t)row0 * C_DIM;

  float4 v[2][4];
#pragma unroll
  for (int j = 0; j < 4; j++) {
    const int c4 = j * 256 + lane * 4;
    float4 xv[4];
#pragma unroll
    for (int m = 0; m < 4; m++) {
      const int lm = l0 + m - 1;
      if (lm >= 0 && lm < L_DIM)
        xv[m] = *(const float4*)(xr + ((long)m - 1) * C_DIM + c4);
      else
        xv[m] = make_float4(0.f, 0.f, 0.f, 0.f);
    }
#pragma unroll
    for (int r = 0; r < 2; r++)
      stbf4(xbb + (size_t)(row0 + r) * C_DIM + c4, xv[r + 1]);

    const float4 w0 = *(const float4*)(dw_w + (size_t)c4 * 3);
    const float4 w1 = *(const float4*)(dw_w + (size_t)c4 * 3 + 4);
    const float4 w2 = *(const float4*)(dw_w + (size_t)c4 * 3 + 8);
    const float4 bb = *(const float4*)(dw_b + c4);
#pragma unroll
    for (int r = 0; r < 2; r++) {
      const float4 xm = xv[r], x0 = xv[r + 1], xq = xv[r + 2];
      v[r][j].x = xm.x * w0.x + x0.x * w0.y + xq.x * w0.z + bb.x;
      v[r][j].y = xm.y * w0.w + x0.y * w1.x + xq.y * w1.y + bb.y;
      v[r][j].z = xm.z * w1.z + x0.z * w1.w + xq.z * w2.x + bb.z;
      v[r][j].w = xm.w * w2.y + x0.w * w2.z + xq.w * w2.w + bb.w;
    }
  }

  float mu[2], rstd[2];
#pragma unroll
  for (int r = 0; r < 2; r++) {
    float s1 = 0.f, s2 = 0.f;
#pragma unroll
    for (int j = 0; j < 4; j++) {
      s1 += v[r][j].x + v[r][j].y + v[r][j].z + v[r][j].w;
      s2 += v[r][j].x * v[r][j].x + v[r][j].y * v[r][j].y
          + v[r][j].z * v[r][j].z + v[r][j].w * v[r][j].w;
    }
    const float t1 = s1 + __shfl_xor(s1, 32);
    const float t2 = s2 + __shfl_xor(s2, 32);
    float cc = (lane < 32) ? t1 : t2;
#pragma unroll
    for (int m = 16; m >= 1; m >>= 1) cc += __shfl_xor(cc, m);
    const float dd = __shfl_xor(cc, 32);
    const float S1 = (lane < 32) ? cc : dd;
    const float S2 = (lane < 32) ? dd : cc;
    mu[r]   = S1 * (1.f / C_DIM);
    rstd[r] = rsqrtf(S2 * (1.f / C_DIM) - mu[r] * mu[r] + 1e-5f);
  }

  float po[2][7] = {}, pm[2][7] = {};
#pragma unroll
  for (int j = 0; j < 4; j++) {
    const int c4 = j * 256 + lane * 4;
    const float4 gg = *(const float4*)&slng[c4];
    const float4 bb = *(const float4*)&slnb[c4];
    float4 g[2];
#pragma unroll
    for (int r = 0; r < 2; r++) {
      g[r].x = gelu_fast((v[r][j].x - mu[r]) * rstd[r] * gg.x + bb.x);
      g[r].y = gelu_fast((v[r][j].y - mu[r]) * rstd[r] * gg.y + bb.y);
      g[r].z = gelu_fast((v[r][j].z - mu[r]) * rstd[r] * gg.z + bb.z);
      g[r].w = gelu_fast((v[r][j].w - mu[r]) * rstd[r] * gg.w + bb.w);
    }
#pragma unroll
    for (int k = 0; k < 7; k++) {
      const float4 wo = *(const float4*)&sWo[k * 1024 + c4];
      const float4 wm = *(const float4*)&sWm[k * 1024 + c4];
#pragma unroll
      for (int r = 0; r < 2; r++) {
        po[r][k] += g[r].x * wo.x + g[r].y * wo.y + g[r].z * wo.z + g[r].w * wo.w;
        pm[r][k] += g[r].x * wm.x + g[r].y * wm.y + g[r].z * wm.z + g[r].w * wm.w;
      }
    }
  }

  float poS[2][7], pmS[2][7];
#pragma unroll
  for (int r = 0; r < 2; r++)
#pragma unroll
    for (int k = 0; k < 7; k++) {
      const float tp = po[r][k] + __shfl_xor(po[r][k], 32);
      const float tm = pm[r][k] + __shfl_xor(pm[r][k], 32);
      float cc = (lane < 32) ? tp : tm;
#pragma unroll
      for (int m = 16; m >= 1; m >>= 1) cc += __shfl_xor(cc, m);
      const float dd = __shfl_xor(cc, 32);
      poS[r][k] = (lane < 32) ? cc : dd;
      pmS[r][k] = (lane < 32) ? dd : cc;
    }

#pragma unroll
  for (int r = 0; r < 2; r++) {
    float lg[7], mx = -1e30f;
#pragma unroll
    for (int k = 0; k < 7; k++) { lg[k] = pmS[r][k] + bmb[k]; mx = fmaxf(mx, lg[k]); }
    float se = 0.f, e[7];
#pragma unroll
    for (int k = 0; k < 7; k++) { e[k] = __expf(lg[k] - mx); se += e[k]; }
    const float inv = 1.f / se;
    const int l = l0 + r;

    if (lane == r) {
      float pk[32];
#pragma unroll
      for (int k = 0; k < 7; k++) {
        const float msk = e[k] * inv;
        const float off = (poS[r][k] + bo[k]) * 2.0f;
        const float ap  = (float)l + (float)(k - 3) + off;
        const float apc = fminf(fmaxf(ap, 0.f), (float)(L_DIM - 1));
        int f = (int)apc;
        int c = f + 1; if (c > L_DIM - 1) c = L_DIM - 1;
        const float w1  = apc - (float)f;
        const float val = (ap < 0.f || ap > (float)(L_DIM - 1)) ? 0.f : 1.f;
        pk[k]      = (1.f - w1) * val * msk;
        pk[8 + k]  = w1 * val * msk;
        pk[16 + k] = (float)f;
        pk[24 + k] = (float)c;
      }
      pk[7] = pk[15] = pk[23] = pk[31] = 0.f;
      float* cr = coef + (size_t)(row0 + r) * 32;
#pragma unroll
      for (int q = 0; q < 8; q++)
        *(float4*)(cr + q * 4) = make_float4(pk[q*4], pk[q*4+1], pk[q*4+2], pk[q*4+3]);
    }
  }
}

// ====== L2: wcomb (blocks 0..63) + gather (blocks 64..1087) ==================
// wcomb: Wcb = Woutb @ WiT^T (1024^3), waves 0..3 run the gemm body, waves
// 4..7 execute the EXACT matching 17 __syncthreads (1 prologue + 16 iters).
// gather: 8 rows/block (wave per row), coef+xbb -> gb, sArr.
__global__ __launch_bounds__(512, 2)
void wcomb_gather(const __hip_bfloat16* __restrict__ Woutb,
                  const __hip_bfloat16* __restrict__ WiT,
                  __hip_bfloat16* __restrict__ Wcb,
                  const float* __restrict__ coef,
                  const __hip_bfloat16* __restrict__ xbb,
                  __hip_bfloat16* __restrict__ gb,
                  float* __restrict__ sArr)
{
  __shared__ __hip_bfloat16 As[2][2][128 * 32];
  __shared__ __hip_bfloat16 Bs[2][2][128 * 32];
  const int tid  = threadIdx.x;
  const int lane = tid & 63;
  const int wid  = tid >> 6;

  if (blockIdx.x < 64) {
    // ---------- W_comb GEMM, 128x128 tile, K=1024 (16 iters) ----------
    if (wid >= 4) {           // idle waves: match barrier count exactly (17)
      for (int i = 0; i < 17; i++) __syncthreads();
      return;
    }
    const int bm = (int)(blockIdx.x >> 3) * 128;
    const int bn = (int)(blockIdx.x & 7) * 128;
    const int wr = (wid >> 1) * 64;
    const int wc = (wid & 1) * 64;
    const int srow  = tid >> 2;       // 0..63
    const int skoff = (tid & 3) * 8;
    const int K = C_DIM;

    const __hip_bfloat16* gA0 = Woutb + (size_t)(bm + srow) * K + skoff;
    const __hip_bfloat16* gA1 = Woutb + (size_t)(bm + 64 + srow) * K + skoff;
    const __hip_bfloat16* gB0 = WiT   + (size_t)(bn + srow) * K + skoff;
    const __hip_bfloat16* gB1 = WiT   + (size_t)(bn + 64 + srow) * K + skoff;

    f32x16 acc[2][2] = {};
    const int arow  = lane & 31;
    const int akoff = (lane >> 5) * 8;

#define WSTAGE(k0, buf)                                       \
  do {                                                        \
    gl_lds16(gA0 + (k0),      &As[buf][0][tid * 8]);          \
    gl_lds16(gA1 + (k0),      &As[buf][0][2048 + tid * 8]);   \
    gl_lds16(gA0 + (k0) + 32, &As[buf][1][tid * 8]);          \
    gl_lds16(gA1 + (k0) + 32, &As[buf][1][2048 + tid * 8]);   \
    gl_lds16(gB0 + (k0),      &Bs[buf][0][tid * 8]);          \
    gl_lds16(gB1 + (k0),      &Bs[buf][0][2048 + tid * 8]);   \
    gl_lds16(gB0 + (k0) + 32, &Bs[buf][1][tid * 8]);          \
    gl_lds16(gB1 + (k0) + 32, &Bs[buf][1][2048 + tid * 8]);   \
  } while (0)

    WSTAGE(0, 0);
    __syncthreads();                       // barrier 1
    for (int it = 0; it < 16; ++it) {      // barriers 2..17
      const int cur = it & 1;
      if (it + 1 < 16) WSTAGE((it + 1) * 64, cur ^ 1);
#pragma unroll
      for (int p = 0; p < 2; ++p)
#pragma unroll
        for (int h = 0; h < 2; ++h) {
          const frag8 a0 = *(const frag8*)&As[cur][p][(wr + arow) * 32 + h * 16 + akoff];
          const frag8 a1 = *(const frag8*)&As[cur][p][(wr + 32 + arow) * 32 + h * 16 + akoff];
          const frag8 b0 = *(const frag8*)&Bs[cur][p][(wc + arow) * 32 + h * 16 + akoff];
          const frag8 b1 = *(const frag8*)&Bs[cur][p][(wc + 32 + arow) * 32 + h * 16 + akoff];
          acc[0][0] = __builtin_amdgcn_mfma_f32_32x32x16_bf16(a0, b0, acc[0][0], 0, 0, 0);
          acc[0][1] = __builtin_amdgcn_mfma_f32_32x32x16_bf16(a0, b1, acc[0][1], 0, 0, 0);
          acc[1][0] = __builtin_amdgcn_mfma_f32_32x32x16_bf16(a1, b0, acc[1][0], 0, 0, 0);
          acc[1][1] = __builtin_amdgcn_mfma_f32_32x32x16_bf16(a1, b1, acc[1][1], 0, 0, 0);
        }
      __syncthreads();
    }
#undef WSTAGE

#pragma unroll
    for (int i = 0; i < 2; i++)
#pragma unroll
      for (int j = 0; j < 2; j++) {
        const int col = bn + wc + j * 32 + (lane & 31);
#pragma unroll
        for (int r = 0; r < 16; r++) {
          const int row = bm + wr + i * 32 + (r & 3) + 8 * (r >> 2) + 4 * (lane >> 5);
          Wcb[(size_t)row * C_DIM + col] = __float2bfloat16(acc[i][j][r]);
        }
      }
    return;
  }

  // ---------- gather: 8 rows/block, wave per row ----------
  const int b   = (int)blockIdx.x - 64;        // 0..1023
  const int bs  = (b & 7) * 128 + (b >> 3);    // XCD-contiguous spans
  const int row = bs * 8 + wid;
  const int n   = row >> 11;

  const float* cr = coef + (size_t)row * 32;
  const float4 q0 = *(const float4*)(cr);
  const float4 q1 = *(const float4*)(cr + 4);
  const float4 q2 = *(const float4*)(cr + 8);
  const float4 q3 = *(const float4*)(cr + 12);
  const float4 q4 = *(const float4*)(cr + 16);
  const float4 q5 = *(const float4*)(cr + 20);
  const float4 q6 = *(const float4*)(cr + 24);
  const float4 q7 = *(const float4*)(cr + 28);

  const float wf[7] = {q0.x, q0.y, q0.z, q0.w, q1.x, q1.y, q1.z};
  const float wc[7] = {q2.x, q2.y, q2.z, q2.w, q3.x, q3.y, q3.z};
  const int   pf[7] = {(int)q4.x, (int)q4.y, (int)q4.z, (int)q4.w, (int)q5.x, (int)q5.y, (int)q5.z};
  const int   pc[7] = {(int)q6.x, (int)q6.y, (int)q6.z, (int)q6.w, (int)q7.x, (int)q7.y, (int)q7.z};

  if (lane == 0) {
    sArr[row] = q0.x + q0.y + q0.z + q0.w + q1.x + q1.y + q1.z
              + q2.x + q2.y + q2.z + q2.w + q3.x + q3.y + q3.z;
  }

  const __hip_bfloat16* xpn = xbb + ((size_t)n * L_DIM) * C_DIM;
  __hip_bfloat16* so = gb + (size_t)row * C_DIM;

#pragma unroll
  for (int j = 0; j < 2; j++) {
    const int c8 = j * 512 + lane * 8;
    float a[8] = {0.f, 0.f, 0.f, 0.f, 0.f, 0.f, 0.f, 0.f};
#pragma unroll
    for (int k = 0; k < 7; k++) {
      union { int4 q; __hip_bfloat16 h[8]; } uf, uc;
      uf.q = *(const int4*)(xpn + (size_t)pf[k] * C_DIM + c8);
      uc.q = *(const int4*)(xpn + (size_t)pc[k] * C_DIM + c8);
#pragma unroll
      for (int t = 0; t < 8; t++)
        a[t] += wf[k] * (float)uf.h[t] + wc[k] * (float)uc.h[t];
    }
    union { int4 q; __hip_bfloat16 h[8]; } uo;
#pragma unroll
    for (int t = 0; t < 8; t++) uo.h[t] = __float2bfloat16(a[t]);
    *(int4*)(so + c8) = uo.q;
  }
}

// ------- mid v4 kept for small-workspace fallback paths -------
__global__ __launch_bounds__(256)
void mid_fused_v4(const float* __restrict__ x,
                  const float* __restrict__ dw_w, const float* __restrict__ dw_b,
                  const float* __restrict__ ln_g, const float* __restrict__ ln_b,
                  const float* __restrict__ Wo,   const float* __restrict__ bo,
                  const float* __restrict__ Wm,   const float* __restrict__ bmb,
                  const __hip_bfloat16* __restrict__ xp,
                  __hip_bfloat16* __restrict__ smp)
{
  const int b    = blockIdx.x;
  const int bs   = (b & 7) * 256 + (b >> 3);
  const int wid  = threadIdx.x >> 6;
  const int lane = threadIdx.x & 63;
  const int row  = bs * 4 + wid;
  const int l    = row & (L_DIM - 1);
  const int n    = row >> 11;

  const float* xr = x + (size_t)row * C_DIM;

  float4 v[4];
#pragma unroll
  for (int j = 0; j < 4; j++) {
    const int c4 = j * 256 + lane * 4;
    const float4 x0 = *(const float4*)(xr + c4);
    float4 xm = make_float4(0.f, 0.f, 0.f, 0.f);
    float4 xq = make_float4(0.f, 0.f, 0.f, 0.f);
    if (l > 0)         xm = *(const float4*)(xr + c4 - C_DIM);
    if (l < L_DIM - 1) xq = *(const float4*)(xr + c4 + C_DIM);
    const float4 w0 = *(const float4*)(dw_w + (size_t)c4 * 3);
    const float4 w1 = *(const float4*)(dw_w + (size_t)c4 * 3 + 4);
    const float4 w2 = *(const float4*)(dw_w + (size_t)c4 * 3 + 8);
    const float4 bb = *(const float4*)(dw_b + c4);
    v[j].x = xm.x * w0.x + x0.x * w0.y + xq.x * w0.z + bb.x;
    v[j].y = xm.y * w0.w + x0.y * w1.x + xq.y * w1.y + bb.y;
    v[j].z = xm.z * w1.z + x0.z * w1.w + xq.z * w2.x + bb.z;
    v[j].w = xm.w * w2.y + x0.w * w2.z + xq.w * w2.w + bb.w;
  }

  float s1 = 0.f, s2 = 0.f;
#pragma unroll
  for (int j = 0; j < 4; j++) {
    s1 += v[j].x + v[j].y + v[j].z + v[j].w;
    s2 += v[j].x * v[j].x + v[j].y * v[j].y + v[j].z * v[j].z + v[j].w * v[j].w;
  }
#pragma unroll
  for (int m = 1; m < 64; m <<= 1) { s1 += __shfl_xor(s1, m); s2 += __shfl_xor(s2, m); }
  const float mu   = s1 * (1.f / C_DIM);
  const float rstd = rsqrtf(s2 * (1.f / C_DIM) - mu * mu + 1e-5f);

  float4 g[4];
#pragma unroll
  for (int j = 0; j < 4; j++) {
    const int c4 = j * 256 + lane * 4;
    const float4 gg = *(const float4*)(ln_g + c4);
    const float4 bb = *(const float4*)(ln_b + c4);
    g[j].x = gelu_fast((v[j].x - mu) * rstd * gg.x + bb.x);
    g[j].y = gelu_fast((v[j].y - mu) * rstd * gg.y + bb.y);
    g[j].z = gelu_fast((v[j].z - mu) * rstd * gg.z + bb.z);
    g[j].w = gelu_fast((v[j].w - mu) * rstd * gg.w + bb.w);
  }

  float po[7] = {0,0,0,0,0,0,0}, pm[7] = {0,0,0,0,0,0,0};
#pragma unroll
  for (int k = 0; k < 7; k++) {
#pragma unroll
    for (int j = 0; j < 4; j++) {
      const int c4 = j * 256 + lane * 4;
      const float4 wo = *(const float4*)(Wo + (size_t)k * C_DIM + c4);
      const float4 wm = *(const float4*)(Wm + (size_t)k * C_DIM + c4);
      po[k] += g[j].x * wo.x + g[j].y * wo.y + g[j].z * wo.z + g[j].w * wo.w;
      pm[k] += g[j].x * wm.x + g[j].y * wm.y + g[j].z * wm.z + g[j].w * wm.w;
    }
  }
#pragma unroll
  for (int k = 0; k < 7; k++)
#pragma unroll
    for (int m = 1; m < 64; m <<= 1) {
      po[k] += __shfl_xor(po[k], m);
      pm[k] += __shfl_xor(pm[k], m);
    }

  float lg[7], mx = -1e30f;
#pragma unroll
  for (int k = 0; k < 7; k++) { lg[k] = pm[k] + bmb[k]; mx = fmaxf(mx, lg[k]); }
  float se = 0.f, e[7];
#pragma unroll
  for (int k = 0; k < 7; k++) { e[k] = __expf(lg[k] - mx); se += e[k]; }
  const float inv = 1.f / se;

  float wf[7], wcl[7]; int pf[7], pc[7];
#pragma unroll
  for (int k = 0; k < 7; k++) {
    const float msk = e[k] * inv;
    const float off = (po[k] + bo[k]) * 2.0f;
    const float ap  = (float)l + (float)(k - 3) + off;
    const float apc = fminf(fmaxf(ap, 0.f), (float)(L_DIM - 1));
    int f = (int)apc;
    int c = f + 1; if (c > L_DIM - 1) c = L_DIM - 1;
    const float w1  = apc - (float)f;
    const float val = (ap < 0.f || ap > (float)(L_DIM - 1)) ? 0.f : 1.f;
    wf[k]  = (1.f - w1) * val * msk;
    wcl[k] = w1 * val * msk;
    pf[k] = f; pc[k] = c;
  }

  const __hip_bfloat16* xpn = xp + ((size_t)n * L_DIM) * C_DIM;
  __hip_bfloat16* so = smp + (size_t)row * C_DIM;
#pragma unroll
  for (int j = 0; j < 4; j++) {
    const int c4 = j * 256 + lane * 4;
    float4 a = make_float4(0.f, 0.f, 0.f, 0.f);
#pragma unroll
    for (int k = 0; k < 7; k++) {
      const float4 vf = ldbf4(xpn + (size_t)pf[k] * C_DIM + c4);
      const float4 vc = ldbf4(xpn + (size_t)pc[k] * C_DIM + c4);
      a.x += wf[k] * vf.x + wcl[k] * vc.x;
      a.y += wf[k] * vf.y + wcl[k] * vc.y;
      a.z += wf[k] * vf.z + wcl[k] * vc.z;
      a.w += wf[k] * vf.w + wcl[k] * vc.w;
    }
    stbf4(so + c4, a);
  }
}

// ---------------- host ----------------
extern "C" void kernel_launch(void* const* d_in, const int* in_sizes, int n_in,
                              void* d_out, int out_size, void* d_ws, size_t ws_size,
                              hipStream_t stream)
{
  const float* x    = (const float*)d_in[0];
  const float* Wi   = (const float*)d_in[1];
  const float* bi   = (const float*)d_in[2];
  const float* dw_w = (const float*)d_in[3];
  const float* dw_b = (const float*)d_in[4];
  const float* ln_g = (const float*)d_in[5];
  const float* ln_b = (const float*)d_in[6];
  const float* Wo   = (const float*)d_in[7];
  const float* bo   = (const float*)d_in[8];
  const float* Wm   = (const float*)d_in[9];
  const float* bm   = (const float*)d_in[10];
  const float* Wout = (const float*)d_in[11];
  const float* bout = (const float*)d_in[12];
  float* out = (float*)d_out;

  const size_t XE = (size_t)M_DIM * C_DIM;
  const size_t WE = (size_t)C_DIM * C_DIM;
  char* wsb = (char*)d_ws;

  // ---- collapsed-GEMM path layout ----
  __hip_bfloat16* xbb2  = (__hip_bfloat16*)wsb;                       // XE*2
  __hip_bfloat16* gb    = (__hip_bfloat16*)(wsb + XE * 2);            // XE*2
  __hip_bfloat16* Woutb2= (__hip_bfloat16*)(wsb + XE * 4);            // WE*2
  __hip_bfloat16* WiT   = (__hip_bfloat16*)(wsb + XE * 4 + WE * 2);   // WE*2
  __hip_bfloat16* Wcb   = (__hip_bfloat16*)(wsb + XE * 4 + WE * 4);   // WE*2
  float* coef2 = (float*)(wsb + XE * 4 + WE * 6);                     // M*128
  float* sArr  = (float*)(wsb + XE * 4 + WE * 6 + (size_t)M_DIM * 128);
  float* bvec  = (float*)(wsb + XE * 4 + WE * 6 + (size_t)M_DIM * 128 + (size_t)M_DIM * 4);
  const size_t need_v5 = XE * 4 + WE * 6 + (size_t)M_DIM * 132 + 4096;

  // ---- legacy layouts (fallbacks) ----
  __hip_bfloat16* xp    = (__hip_bfloat16*)wsb;
  __hip_bfloat16* smp   = (__hip_bfloat16*)(wsb + XE * 2);
  __hip_bfloat16* Wib   = (__hip_bfloat16*)(wsb + XE * 4);
  __hip_bfloat16* Woutb = (__hip_bfloat16*)(wsb + XE * 4 + WE * 2);
  __hip_bfloat16* xbb   = (__hip_bfloat16*)(wsb + XE * 4 + WE * 4);
  const size_t need_w2   = XE * 4 + WE * 4;
  const size_t need_full = need_w2 + XE * 2;

  dim3 gg(M_DIM / 128, C_DIM / 128);   // 64 x 8

  if (ws_size >= need_v5) {
    // 3-launch collapsed pipeline:
    //   L1: pre_fused + WiT transpose + Wout cvt + bvec   (all independent)
    //   L2: Wcomb GEMM (64 blk) + gather (1024 blk)       (deps on L1 only)
    //   L3: out = gb @ Wcb^T + sArr*bvec + bout
    fused_pre_prep<<<1040, 512, 0, stream>>>(
        x, dw_w, dw_b, ln_g, ln_b, Wo, bo, Wm, bm,
        Wi, Wout, bi, xbb2, coef2, WiT, Woutb2, bvec);
    wcomb_gather<<<1088, 512, 0, stream>>>(
        Woutb2, WiT, Wcb, coef2, xbb2, gb, sArr);
    gemm_db<float><<<gg, 256, 0, stream>>>(
        gb, Wcb, bout, out, M_DIM, C_DIM, C_DIM, sArr, bvec);
  } else if (ws_size >= need_full) {
    cvt_f32_bf16<<<(int)(XE / 8 / 256), 256, 0, stream>>>(x, xbb, (int)(XE / 8));
    cvt_two_f32_bf16<<<(int)(2 * (WE / 8) / 256), 256, 0, stream>>>(
        Wi, Wib, Wout, Woutb, (int)(WE / 8));
    gemm_db<__hip_bfloat16><<<gg, 256, 0, stream>>>(xbb, Wib, bi, xp, M_DIM, C_DIM, C_DIM,
                                                    nullptr, nullptr);
    mid_fused_v4<<<M_DIM / 4, 256, 0, stream>>>(x, dw_w, dw_b, ln_g, ln_b, Wo, bo, Wm, bm, xp, smp);
    gemm_db<float><<<gg, 256, 0, stream>>>(smp, Woutb, bout, out, M_DIM, C_DIM, C_DIM,
                                           nullptr, nullptr);
  } else if (ws_size >= need_w2) {
    cvt_f32_bf16<<<(int)(WE / 8 / 256), 256, 0, stream>>>(Wout, Woutb, (int)(WE / 8));
    gemm_nt<float, __hip_bfloat16><<<gg, 256, 0, stream>>>(x, Wi, bi, xp, M_DIM, C_DIM, C_DIM);
    mid_fused_v4<<<M_DIM / 4, 256, 0, stream>>>(x, dw_w, dw_b, ln_g, ln_b, Wo, bo, Wm, bm, xp, smp);
    gemm_db<float><<<gg, 256, 0, stream>>>(smp, Woutb, bout, out, M_DIM, C_DIM, C_DIM,
                                           nullptr, nullptr);
  } else {
    gemm_nt<float, __hip_bfloat16><<<gg, 256, 0, stream>>>(x, Wi, bi, xp, M_DIM, C_DIM, C_DIM);
    mid_fused_v4<<<M_DIM / 4, 256, 0, stream>>>(x, dw_w, dw_b, ln_g, ln_b, Wo, bo, Wm, bm, xp, smp);
    gemm_nt<__hip_bfloat16, float><<<gg, 256, 0, stream>>>(smp, Wout, bout, out, M_DIM, C_DIM, C_DIM);
  }
}

// Round 7
// 180.549 us; speedup vs baseline: 1.1182x; 1.0261x over previous
//
#include <hip/hip_runtime.h>
#include <hip/hip_bf16.h>
#include <cstdint>

#define C_DIM 1024
#define L_DIM 2048
#define N_DIM 4
#define M_DIM (N_DIM * L_DIM)   // 8192

typedef __attribute__((ext_vector_type(8))) short frag8;    // 8 bf16 = 4 VGPRs
typedef __attribute__((ext_vector_type(4)))  float f32x4;
typedef __attribute__((ext_vector_type(16))) float f32x16;

// ---------------- helpers ----------------
__device__ __forceinline__ void gl_lds16(const void* g, void* l) {
  __builtin_amdgcn_global_load_lds((const __attribute__((address_space(1))) void*)g,
                                   (__attribute__((address_space(3))) void*)l,
                                   16, 0, 0);
}
__device__ __forceinline__ void store_out(float* Y, size_t idx, float v) { Y[idx] = v; }
__device__ __forceinline__ void store_out(__hip_bfloat16* Y, size_t idx, float v) {
  Y[idx] = __float2bfloat16(v);
}
__device__ __forceinline__ float4 ldbf4(const __hip_bfloat16* p) {
  union { short4 s; __hip_bfloat16 h[4]; } u; u.s = *(const short4*)p;
  return make_float4((float)u.h[0], (float)u.h[1], (float)u.h[2], (float)u.h[3]);
}
__device__ __forceinline__ void stbf4(__hip_bfloat16* p, float4 v) {
  union { short4 s; __hip_bfloat16 h[4]; } u;
  u.h[0] = __float2bfloat16(v.x); u.h[1] = __float2bfloat16(v.y);
  u.h[2] = __float2bfloat16(v.z); u.h[3] = __float2bfloat16(v.w);
  *(short4*)p = u.s;
}
// fast GELU (tanh form)
__device__ __forceinline__ float gelu_fast(float t) {
  const float t3 = t * t * t;
  const float ns = -1.5957691216f * t - 0.0713548163f * t3;
  return t / (1.f + __expf(ns));
}

// fp32 -> bf16 bulk convert, 8 elems/thread (fallback paths)
__global__ __launch_bounds__(256)
void cvt_f32_bf16(const float* __restrict__ in, __hip_bfloat16* __restrict__ out, int n8) {
  const int i = blockIdx.x * 256 + threadIdx.x;
  if (i >= n8) return;
  const float4 a = *(const float4*)(in + (size_t)i * 8);
  const float4 b = *(const float4*)(in + (size_t)i * 8 + 4);
  union { __hip_bfloat16 h[8]; int4 q; } u;
  u.h[0] = __float2bfloat16(a.x); u.h[1] = __float2bfloat16(a.y);
  u.h[2] = __float2bfloat16(a.z); u.h[3] = __float2bfloat16(a.w);
  u.h[4] = __float2bfloat16(b.x); u.h[5] = __float2bfloat16(b.y);
  u.h[6] = __float2bfloat16(b.z); u.h[7] = __float2bfloat16(b.w);
  *(int4*)(out + (size_t)i * 8) = u.q;
}

__global__ __launch_bounds__(256)
void cvt_two_f32_bf16(const float* __restrict__ inA, __hip_bfloat16* __restrict__ outA,
                      const float* __restrict__ inB, __hip_bfloat16* __restrict__ outB,
                      int n8each) {
  int i = blockIdx.x * 256 + threadIdx.x;
  const float* in; __hip_bfloat16* out;
  if (i < n8each) { in = inA; out = outA; }
  else            { in = inB; out = outB; i -= n8each; }
  if (i >= n8each) return;
  const float4 a = *(const float4*)(in + (size_t)i * 8);
  const float4 b = *(const float4*)(in + (size_t)i * 8 + 4);
  union { __hip_bfloat16 h[8]; int4 q; } u;
  u.h[0] = __float2bfloat16(a.x); u.h[1] = __float2bfloat16(a.y);
  u.h[2] = __float2bfloat16(a.z); u.h[3] = __float2bfloat16(a.w);
  u.h[4] = __float2bfloat16(b.x); u.h[5] = __float2bfloat16(b.y);
  u.h[6] = __float2bfloat16(b.z); u.h[7] = __float2bfloat16(b.w);
  *(int4*)(out + (size_t)i * 8) = u.q;
}

// ------- GEMM: BK=64, double-buffered LDS, 32x32x16 MFMA, 1 barrier/iter -------
// Y[M,N] = X[M,K] @ W[N,K]^T (+ bias[col]) (+ sArr[row]*bvec[col]).
template <typename TY>
__global__ __launch_bounds__(256, 2)
void gemm_db(const __hip_bfloat16* __restrict__ X,
             const __hip_bfloat16* __restrict__ W,
             const float* __restrict__ bias,
             TY* __restrict__ Y, int M, int N, int K,
             const float* __restrict__ sArr, const float* __restrict__ bvec)
{
  __shared__ __hip_bfloat16 As[2][2][128 * 32];   // [buf][panel]
  __shared__ __hip_bfloat16 Bs[2][2][128 * 32];
  const int tid  = threadIdx.x;
  const int lane = tid & 63;
  const int wave = tid >> 6;
  const int bm = blockIdx.x * 128;
  const int bn = blockIdx.y * 128;
  const int wr = (wave >> 1) * 64;
  const int wc = (wave & 1) * 64;
  const int srow  = tid >> 2;       // 0..63
  const int skoff = (tid & 3) * 8;  // elements

  const __hip_bfloat16* gA0 = X + (size_t)(bm + srow) * K + skoff;
  const __hip_bfloat16* gA1 = X + (size_t)(bm + 64 + srow) * K + skoff;
  const __hip_bfloat16* gB0 = W + (size_t)(bn + srow) * K + skoff;
  const __hip_bfloat16* gB1 = W + (size_t)(bn + 64 + srow) * K + skoff;

  f32x16 acc[2][2] = {};
  const int arow  = lane & 31;
  const int akoff = (lane >> 5) * 8;

#define STAGE(k0, buf)                                        \
  do {                                                        \
    gl_lds16(gA0 + (k0),      &As[buf][0][tid * 8]);          \
    gl_lds16(gA1 + (k0),      &As[buf][0][2048 + tid * 8]);   \
    gl_lds16(gA0 + (k0) + 32, &As[buf][1][tid * 8]);          \
    gl_lds16(gA1 + (k0) + 32, &As[buf][1][2048 + tid * 8]);   \
    gl_lds16(gB0 + (k0),      &Bs[buf][0][tid * 8]);          \
    gl_lds16(gB1 + (k0),      &Bs[buf][0][2048 + tid * 8]);   \
    gl_lds16(gB0 + (k0) + 32, &Bs[buf][1][tid * 8]);          \
    gl_lds16(gB1 + (k0) + 32, &Bs[buf][1][2048 + tid * 8]);   \
  } while (0)

  STAGE(0, 0);
  __syncthreads();
  const int iters = K / 64;
  for (int it = 0; it < iters; ++it) {
    const int cur = it & 1;
    if (it + 1 < iters) STAGE((it + 1) * 64, cur ^ 1);   // prefetch next tile

#pragma unroll
    for (int p = 0; p < 2; ++p)
#pragma unroll
      for (int h = 0; h < 2; ++h) {
        const frag8 a0 = *(const frag8*)&As[cur][p][(wr + arow) * 32 + h * 16 + akoff];
        const frag8 a1 = *(const frag8*)&As[cur][p][(wr + 32 + arow) * 32 + h * 16 + akoff];
        const frag8 b0 = *(const frag8*)&Bs[cur][p][(wc + arow) * 32 + h * 16 + akoff];
        const frag8 b1 = *(const frag8*)&Bs[cur][p][(wc + 32 + arow) * 32 + h * 16 + akoff];
        acc[0][0] = __builtin_amdgcn_mfma_f32_32x32x16_bf16(a0, b0, acc[0][0], 0, 0, 0);
        acc[0][1] = __builtin_amdgcn_mfma_f32_32x32x16_bf16(a0, b1, acc[0][1], 0, 0, 0);
        acc[1][0] = __builtin_amdgcn_mfma_f32_32x32x16_bf16(a1, b0, acc[1][0], 0, 0, 0);
        acc[1][1] = __builtin_amdgcn_mfma_f32_32x32x16_bf16(a1, b1, acc[1][1], 0, 0, 0);
      }
    __syncthreads();   // drains prefetch loads + protects buf reuse
  }
#undef STAGE

  // C/D layout (32x32): col=lane&31, row=(r&3)+8*(r>>2)+4*(lane>>5)  [m74/m101]
#pragma unroll
  for (int i = 0; i < 2; i++)
#pragma unroll
    for (int j = 0; j < 2; j++) {
      const int col = bn + wc + j * 32 + (lane & 31);
      const float bv  = bias ? bias[col] : 0.f;
      const float bvv = (sArr && bvec) ? bvec[col] : 0.f;
#pragma unroll
      for (int r = 0; r < 16; r++) {
        const int row = bm + wr + i * 32 + (r & 3) + 8 * (r >> 2) + 4 * (lane >> 5);
        float extra = bv;
        if (sArr) extra += sArr[row] * bvv;
        store_out(Y, (size_t)row * N + col, acc[i][j][r] + extra);
      }
    }
}

// ---------------- fallback GEMM (16x16, register staging) ----------------
struct Ld8f { float4 a, b; };
struct Ld8b { int4 a; };
__device__ __forceinline__ Ld8f ld8(const float* p) {
  return { *(const float4*)p, *(const float4*)(p + 4) };
}
__device__ __forceinline__ Ld8b ld8(const __hip_bfloat16* p) { return { *(const int4*)p }; }
__device__ __forceinline__ void st8(__hip_bfloat16* l, const Ld8f& v) {
  union { __hip_bfloat16 h[8]; int4 q; } u;
  u.h[0] = __float2bfloat16(v.a.x); u.h[1] = __float2bfloat16(v.a.y);
  u.h[2] = __float2bfloat16(v.a.z); u.h[3] = __float2bfloat16(v.a.w);
  u.h[4] = __float2bfloat16(v.b.x); u.h[5] = __float2bfloat16(v.b.y);
  u.h[6] = __float2bfloat16(v.b.z); u.h[7] = __float2bfloat16(v.b.w);
  *(int4*)l = u.q;
}
__device__ __forceinline__ void st8(__hip_bfloat16* l, const Ld8b& v) { *(int4*)l = v.a; }

template <typename TX, typename TY>
__global__ __launch_bounds__(256, 2)
void gemm_nt(const TX* __restrict__ X, const float* __restrict__ W,
             const float* __restrict__ bias, TY* __restrict__ Y, int M, int N, int K)
{
  __shared__ __hip_bfloat16 As[128 * 32];
  __shared__ __hip_bfloat16 Bs[128 * 32];
  const int tid  = threadIdx.x;
  const int lane = tid & 63;
  const int wave = tid >> 6;
  const int bm = blockIdx.x * 128;
  const int bn = blockIdx.y * 128;
  const int wr = (wave >> 1) * 64;
  const int wc = (wave & 1) * 64;
  const int srow  = tid >> 2;
  const int skoff = (tid & 3) * 8;

  f32x4 acc[4][4] = {};
  const TX*    gA0 = X + (size_t)(bm + srow) * K + skoff;
  const TX*    gA1 = X + (size_t)(bm + 64 + srow) * K + skoff;
  const float* gB0 = W + (size_t)(bn + srow) * K + skoff;
  const float* gB1 = W + (size_t)(bn + 64 + srow) * K + skoff;
  const int arow  = lane & 15;
  const int akoff = (lane >> 4) * 8;

  for (int k0 = 0; k0 < K; k0 += 32) {
    const auto va0 = ld8(gA0 + k0);
    const auto va1 = ld8(gA1 + k0);
    const auto vb0 = ld8(gB0 + k0);
    const auto vb1 = ld8(gB1 + k0);
    __syncthreads();
    st8(&As[srow * 32 + skoff],        va0);
    st8(&As[(64 + srow) * 32 + skoff], va1);
    st8(&Bs[srow * 32 + skoff],        vb0);
    st8(&Bs[(64 + srow) * 32 + skoff], vb1);
    __syncthreads();

    frag8 a[4], b[4];
#pragma unroll
    for (int i = 0; i < 4; i++)
      a[i] = *(const frag8*)&As[(wr + i * 16 + arow) * 32 + akoff];
#pragma unroll
    for (int j = 0; j < 4; j++)
      b[j] = *(const frag8*)&Bs[(wc + j * 16 + arow) * 32 + akoff];
#pragma unroll
    for (int i = 0; i < 4; i++)
#pragma unroll
      for (int j = 0; j < 4; j++)
        acc[i][j] = __builtin_amdgcn_mfma_f32_16x16x32_bf16(a[i], b[j], acc[i][j], 0, 0, 0);
  }
#pragma unroll
  for (int i = 0; i < 4; i++)
#pragma unroll
    for (int j = 0; j < 4; j++) {
      const int col = bn + wc + j * 16 + (lane & 15);
      const float bv = bias[col];
#pragma unroll
      for (int r = 0; r < 4; r++) {
        const int row = bm + wr + i * 16 + (lane >> 4) * 4 + r;
        store_out(Y, (size_t)row * N + col, acc[i][j][r] + bv);
      }
    }
}

// ====== L1: pre_aux ==========================================================
// Aux blocks FIRST (short, input-only), heavy pre_fused blocks after:
//   blocks 0..255   : Wi f32 -> WiT bf16 transpose (64x64 LDS tiles)
//   blocks 256..511 : Wout f32 -> bf16 (16 elems/thread)
//   blocks 512..767 : bvec = Wout @ bi (4 rows/block, wave per row)
//   blocks 768..1279: pre_fused v2 body (256 thr, 4 waves x 4 rows, 64KB stage)
// Aux-first ordering: aux drains while heavy blocks stream in behind (perf
// heuristic only; all blocks read only kernel inputs -> order-independent).
__global__ __launch_bounds__(256, 2)
void pre_aux(const float* __restrict__ x,
             const float* __restrict__ dw_w, const float* __restrict__ dw_b,
             const float* __restrict__ ln_g, const float* __restrict__ ln_b,
             const float* __restrict__ Wo,   const float* __restrict__ bo,
             const float* __restrict__ Wm,   const float* __restrict__ bmb,
             const float* __restrict__ Wi,   const float* __restrict__ Wout,
             const float* __restrict__ bi,
             __hip_bfloat16* __restrict__ xbb,
             float* __restrict__ coef,
             __hip_bfloat16* __restrict__ WiT,
             __hip_bfloat16* __restrict__ Woutb,
             float* __restrict__ bvec)
{
  __shared__ float smem[16384];        // 64 KB, aliased per branch
  const int blk  = blockIdx.x;
  const int tid  = threadIdx.x;
  const int lane = tid & 63;
  const int wid  = tid >> 6;

  if (blk < 256) {                     // ---- Wi transpose -> WiT bf16 ----
    float (*tile)[65] = (float(*)[65])smem;    // 64x65 f32 = 16.6 KB
    const int bi_ = blk >> 4;          // j-block
    const int bj  = blk & 15;          // k-block
    const int r   = tid >> 2;          // 0..63
    const int c0  = (tid & 3) * 16;    // 0,16,32,48
    const float* src = Wi + (size_t)(bi_ * 64 + r) * C_DIM + bj * 64 + c0;
    *(float4*)&tile[r][c0]      = *(const float4*)(src);
    *(float4*)&tile[r][c0 + 4]  = *(const float4*)(src + 4);
    *(float4*)&tile[r][c0 + 8]  = *(const float4*)(src + 8);
    *(float4*)&tile[r][c0 + 12] = *(const float4*)(src + 12);
    __syncthreads();
    __hip_bfloat16* dst = WiT + (size_t)(bj * 64 + r) * C_DIM + bi_ * 64 + c0;
    union { __hip_bfloat16 h[16]; int4 q[2]; } u;
#pragma unroll
    for (int i = 0; i < 16; i++) u.h[i] = __float2bfloat16(tile[c0 + i][r]);
    *(int4*)(dst)     = u.q[0];
    *(int4*)(dst + 8) = u.q[1];
    return;
  }
  if (blk < 512) {                     // ---- Wout -> bf16 (16 elems/thread) ----
    const size_t base = ((size_t)(blk - 256) * 256 + tid) * 16;
#pragma unroll
    for (int h = 0; h < 2; h++) {
      const float4 a = *(const float4*)(Wout + base + h * 8);
      const float4 c = *(const float4*)(Wout + base + h * 8 + 4);
      union { __hip_bfloat16 h8[8]; int4 q; } u;
      u.h8[0] = __float2bfloat16(a.x); u.h8[1] = __float2bfloat16(a.y);
      u.h8[2] = __float2bfloat16(a.z); u.h8[3] = __float2bfloat16(a.w);
      u.h8[4] = __float2bfloat16(c.x); u.h8[5] = __float2bfloat16(c.y);
      u.h8[6] = __float2bfloat16(c.z); u.h8[7] = __float2bfloat16(c.w);
      *(int4*)(Woutb + base + h * 8) = u.q;
    }
    return;
  }
  if (blk < 768) {                     // ---- bvec = Wout @ bi ----
    const int row = (blk - 512) * 4 + wid;
    const float* wr_ = Wout + (size_t)row * C_DIM;
    float s = 0.f;
#pragma unroll
    for (int c = 0; c < 4; c++) {
      const int j = c * 256 + lane * 4;
      const float4 w  = *(const float4*)(wr_ + j);
      const float4 bb = *(const float4*)(bi + j);
      s += w.x * bb.x + w.y * bb.y + w.z * bb.z + w.w * bb.w;
    }
#pragma unroll
    for (int m = 1; m < 64; m <<= 1) s += __shfl_xor(s, m);
    if (lane == 0) bvec[row] = s;
    return;
  }

  // ---- pre_fused v2 body (blocks 768..1279 -> b in 0..511) ----
  float* sWo  = smem;
  float* sWm  = smem + 7168;
  float* slng = smem + 14336;
  float* slnb = smem + 15360;

#pragma unroll
  for (int i = 0; i < 7; i++)
    gl_lds16(Wo + (size_t)(i * 256 + tid) * 4, &sWo[(i * 256 + tid) * 4]);
#pragma unroll
  for (int i = 0; i < 7; i++)
    gl_lds16(Wm + (size_t)(i * 256 + tid) * 4, &sWm[(i * 256 + tid) * 4]);
  gl_lds16(ln_g + (size_t)tid * 4, &slng[tid * 4]);
  gl_lds16(ln_b + (size_t)tid * 4, &slnb[tid * 4]);
  __syncthreads();   // drains global_load_lds

  const int b    = blk - 768;                // 0..511
  const int bs   = (b & 7) * 64 + (b >> 3);  // XCD-contiguous row spans
  const int row0 = bs * 16 + wid * 4;        // wave's first row (4 consecutive)
  const int l0   = row0 & (L_DIM - 1);

  const float* xr = x + (size_t)row0 * C_DIM;

  // pass 1: depthwise conv (k=3) for 4 rows; bf16 x-copy for the gather
  float4 v[4][4];   // [row][chunk]
#pragma unroll
  for (int j = 0; j < 4; j++) {
    const int c4 = j * 256 + lane * 4;
    float4 xv[6];
#pragma unroll
    for (int m = 0; m < 6; m++) {
      const int lm = l0 + m - 1;
      if (lm >= 0 && lm < L_DIM)
        xv[m] = *(const float4*)(xr + ((long)m - 1) * C_DIM + c4);
      else
        xv[m] = make_float4(0.f, 0.f, 0.f, 0.f);
    }
#pragma unroll
    for (int r = 0; r < 4; r++)
      stbf4(xbb + (size_t)(row0 + r) * C_DIM + c4, xv[r + 1]);

    const float4 w0 = *(const float4*)(dw_w + (size_t)c4 * 3);
    const float4 w1 = *(const float4*)(dw_w + (size_t)c4 * 3 + 4);
    const float4 w2 = *(const float4*)(dw_w + (size_t)c4 * 3 + 8);
    const float4 bb = *(const float4*)(dw_b + c4);
#pragma unroll
    for (int r = 0; r < 4; r++) {
      const float4 xm = xv[r], x0 = xv[r + 1], xq = xv[r + 2];
      v[r][j].x = xm.x * w0.x + x0.x * w0.y + xq.x * w0.z + bb.x;
      v[r][j].y = xm.y * w0.w + x0.y * w1.x + xq.y * w1.y + bb.y;
      v[r][j].z = xm.z * w1.z + x0.z * w1.w + xq.z * w2.x + bb.z;
      v[r][j].w = xm.w * w2.y + x0.w * w2.z + xq.w * w2.w + bb.w;
    }
  }

  // LayerNorm stats per row (pair-merged s1/s2 butterfly)
  float mu[4], rstd[4];
#pragma unroll
  for (int r = 0; r < 4; r++) {
    float s1 = 0.f, s2 = 0.f;
#pragma unroll
    for (int j = 0; j < 4; j++) {
      s1 += v[r][j].x + v[r][j].y + v[r][j].z + v[r][j].w;
      s2 += v[r][j].x * v[r][j].x + v[r][j].y * v[r][j].y
          + v[r][j].z * v[r][j].z + v[r][j].w * v[r][j].w;
    }
    const float t1 = s1 + __shfl_xor(s1, 32);
    const float t2 = s2 + __shfl_xor(s2, 32);
    float cc = (lane < 32) ? t1 : t2;
#pragma unroll
    for (int m = 16; m >= 1; m >>= 1) cc += __shfl_xor(cc, m);
    const float dd = __shfl_xor(cc, 32);
    const float S1 = (lane < 32) ? cc : dd;
    const float S2 = (lane < 32) ? dd : cc;
    mu[r]   = S1 * (1.f / C_DIM);
    rstd[r] = rsqrtf(S2 * (1.f / C_DIM) - mu[r] * mu[r] + 1e-5f);
  }

  // pass 2: LN + GELU + offset/mask projections (weights from LDS)
  float po[4][7] = {}, pm[4][7] = {};
#pragma unroll
  for (int j = 0; j < 4; j++) {
    const int c4 = j * 256 + lane * 4;
    const float4 gg = *(const float4*)&slng[c4];
    const float4 bb = *(const float4*)&slnb[c4];
    float4 g[4];
#pragma unroll
    for (int r = 0; r < 4; r++) {
      g[r].x = gelu_fast((v[r][j].x - mu[r]) * rstd[r] * gg.x + bb.x);
      g[r].y = gelu_fast((v[r][j].y - mu[r]) * rstd[r] * gg.y + bb.y);
      g[r].z = gelu_fast((v[r][j].z - mu[r]) * rstd[r] * gg.z + bb.z);
      g[r].w = gelu_fast((v[r][j].w - mu[r]) * rstd[r] * gg.w + bb.w);
    }
#pragma unroll
    for (int k = 0; k < 7; k++) {
      const float4 wo = *(const float4*)&sWo[k * 1024 + c4];
      const float4 wm = *(const float4*)&sWm[k * 1024 + c4];
#pragma unroll
      for (int r = 0; r < 4; r++) {
        po[r][k] += g[r].x * wo.x + g[r].y * wo.y + g[r].z * wo.z + g[r].w * wo.w;
        pm[r][k] += g[r].x * wm.x + g[r].y * wm.y + g[r].z * wm.z + g[r].w * wm.w;
      }
    }
  }

  // pair-merged reductions: (po,pm) share one butterfly
  float poS[4][7], pmS[4][7];
#pragma unroll
  for (int r = 0; r < 4; r++)
#pragma unroll
    for (int k = 0; k < 7; k++) {
      const float tp = po[r][k] + __shfl_xor(po[r][k], 32);
      const float tm = pm[r][k] + __shfl_xor(pm[r][k], 32);
      float cc = (lane < 32) ? tp : tm;
#pragma unroll
      for (int m = 16; m >= 1; m >>= 1) cc += __shfl_xor(cc, m);
      const float dd = __shfl_xor(cc, 32);
      poS[r][k] = (lane < 32) ? cc : dd;
      pmS[r][k] = (lane < 32) ? dd : cc;
    }

  // softmax + coef table (one writer lane per row)
#pragma unroll
  for (int r = 0; r < 4; r++) {
    float lg[7], mx = -1e30f;
#pragma unroll
    for (int k = 0; k < 7; k++) { lg[k] = pmS[r][k] + bmb[k]; mx = fmaxf(mx, lg[k]); }
    float se = 0.f, e[7];
#pragma unroll
    for (int k = 0; k < 7; k++) { e[k] = __expf(lg[k] - mx); se += e[k]; }
    const float inv = 1.f / se;
    const int l = l0 + r;

    if (lane == r) {
      float pk[32];
#pragma unroll
      for (int k = 0; k < 7; k++) {
        const float msk = e[k] * inv;
        const float off = (poS[r][k] + bo[k]) * 2.0f;
        const float ap  = (float)l + (float)(k - 3) + off;
        const float apc = fminf(fmaxf(ap, 0.f), (float)(L_DIM - 1));
        int f = (int)apc;
        int c = f + 1; if (c > L_DIM - 1) c = L_DIM - 1;
        const float w1  = apc - (float)f;
        const float val = (ap < 0.f || ap > (float)(L_DIM - 1)) ? 0.f : 1.f;
        pk[k]      = (1.f - w1) * val * msk;   // wf (mask folded in)
        pk[8 + k]  = w1 * val * msk;           // wc
        pk[16 + k] = (float)f;                 // pf
        pk[24 + k] = (float)c;                 // pc
      }
      pk[7] = pk[15] = pk[23] = pk[31] = 0.f;
      float* cr = coef + (size_t)(row0 + r) * 32;
#pragma unroll
      for (int q = 0; q < 8; q++)
        *(float4*)(cr + q * 4) = make_float4(pk[q*4], pk[q*4+1], pk[q*4+2], pk[q*4+3]);
    }
  }
}

// ====== L2: wcomb (blocks 0..63) + gather (blocks 64..1087) ==================
// wcomb: Wcb = Woutb @ WiT^T (1024^3), waves 0..3 run the gemm body, waves
// 4..7 execute the EXACT matching 17 __syncthreads (1 prologue + 16 iters).
// gather: 8 rows/block (wave per row), coef+xbb -> gb, sArr.
__global__ __launch_bounds__(512, 2)
void wcomb_gather(const __hip_bfloat16* __restrict__ Woutb,
                  const __hip_bfloat16* __restrict__ WiT,
                  __hip_bfloat16* __restrict__ Wcb,
                  const float* __restrict__ coef,
                  const __hip_bfloat16* __restrict__ xbb,
                  __hip_bfloat16* __restrict__ gb,
                  float* __restrict__ sArr)
{
  __shared__ __hip_bfloat16 As[2][2][128 * 32];
  __shared__ __hip_bfloat16 Bs[2][2][128 * 32];
  const int tid  = threadIdx.x;
  const int lane = tid & 63;
  const int wid  = tid >> 6;

  if (blockIdx.x < 64) {
    // ---------- W_comb GEMM, 128x128 tile, K=1024 (16 iters) ----------
    if (wid >= 4) {           // idle waves: match barrier count exactly (17)
      for (int i = 0; i < 17; i++) __syncthreads();
      return;
    }
    const int bm = (int)(blockIdx.x >> 3) * 128;
    const int bn = (int)(blockIdx.x & 7) * 128;
    const int wr = (wid >> 1) * 64;
    const int wc = (wid & 1) * 64;
    const int srow  = tid >> 2;       // 0..63
    const int skoff = (tid & 3) * 8;
    const int K = C_DIM;

    const __hip_bfloat16* gA0 = Woutb + (size_t)(bm + srow) * K + skoff;
    const __hip_bfloat16* gA1 = Woutb + (size_t)(bm + 64 + srow) * K + skoff;
    const __hip_bfloat16* gB0 = WiT   + (size_t)(bn + srow) * K + skoff;
    const __hip_bfloat16* gB1 = WiT   + (size_t)(bn + 64 + srow) * K + skoff;

    f32x16 acc[2][2] = {};
    const int arow  = lane & 31;
    const int akoff = (lane >> 5) * 8;

#define WSTAGE(k0, buf)                                       \
  do {                                                        \
    gl_lds16(gA0 + (k0),      &As[buf][0][tid * 8]);          \
    gl_lds16(gA1 + (k0),      &As[buf][0][2048 + tid * 8]);   \
    gl_lds16(gA0 + (k0) + 32, &As[buf][1][tid * 8]);          \
    gl_lds16(gA1 + (k0) + 32, &As[buf][1][2048 + tid * 8]);   \
    gl_lds16(gB0 + (k0),      &Bs[buf][0][tid * 8]);          \
    gl_lds16(gB1 + (k0),      &Bs[buf][0][2048 + tid * 8]);   \
    gl_lds16(gB0 + (k0) + 32, &Bs[buf][1][tid * 8]);          \
    gl_lds16(gB1 + (k0) + 32, &Bs[buf][1][2048 + tid * 8]);   \
  } while (0)

    WSTAGE(0, 0);
    __syncthreads();                       // barrier 1
    for (int it = 0; it < 16; ++it) {      // barriers 2..17
      const int cur = it & 1;
      if (it + 1 < 16) WSTAGE((it + 1) * 64, cur ^ 1);
#pragma unroll
      for (int p = 0; p < 2; ++p)
#pragma unroll
        for (int h = 0; h < 2; ++h) {
          const frag8 a0 = *(const frag8*)&As[cur][p][(wr + arow) * 32 + h * 16 + akoff];
          const frag8 a1 = *(const frag8*)&As[cur][p][(wr + 32 + arow) * 32 + h * 16 + akoff];
          const frag8 b0 = *(const frag8*)&Bs[cur][p][(wc + arow) * 32 + h * 16 + akoff];
          const frag8 b1 = *(const frag8*)&Bs[cur][p][(wc + 32 + arow) * 32 + h * 16 + akoff];
          acc[0][0] = __builtin_amdgcn_mfma_f32_32x32x16_bf16(a0, b0, acc[0][0], 0, 0, 0);
          acc[0][1] = __builtin_amdgcn_mfma_f32_32x32x16_bf16(a0, b1, acc[0][1], 0, 0, 0);
          acc[1][0] = __builtin_amdgcn_mfma_f32_32x32x16_bf16(a1, b0, acc[1][0], 0, 0, 0);
          acc[1][1] = __builtin_amdgcn_mfma_f32_32x32x16_bf16(a1, b1, acc[1][1], 0, 0, 0);
        }
      __syncthreads();
    }
#undef WSTAGE

#pragma unroll
    for (int i = 0; i < 2; i++)
#pragma unroll
      for (int j = 0; j < 2; j++) {
        const int col = bn + wc + j * 32 + (lane & 31);
#pragma unroll
        for (int r = 0; r < 16; r++) {
          const int row = bm + wr + i * 32 + (r & 3) + 8 * (r >> 2) + 4 * (lane >> 5);
          Wcb[(size_t)row * C_DIM + col] = __float2bfloat16(acc[i][j][r]);
        }
      }
    return;
  }

  // ---------- gather: 8 rows/block, wave per row ----------
  const int b   = (int)blockIdx.x - 64;        // 0..1023
  const int bs  = (b & 7) * 128 + (b >> 3);    // XCD-contiguous spans
  const int row = bs * 8 + wid;
  const int n   = row >> 11;

  const float* cr = coef + (size_t)row * 32;
  const float4 q0 = *(const float4*)(cr);
  const float4 q1 = *(const float4*)(cr + 4);
  const float4 q2 = *(const float4*)(cr + 8);
  const float4 q3 = *(const float4*)(cr + 12);
  const float4 q4 = *(const float4*)(cr + 16);
  const float4 q5 = *(const float4*)(cr + 20);
  const float4 q6 = *(const float4*)(cr + 24);
  const float4 q7 = *(const float4*)(cr + 28);

  const float wf[7] = {q0.x, q0.y, q0.z, q0.w, q1.x, q1.y, q1.z};
  const float wc[7] = {q2.x, q2.y, q2.z, q2.w, q3.x, q3.y, q3.z};
  const int   pf[7] = {(int)q4.x, (int)q4.y, (int)q4.z, (int)q4.w, (int)q5.x, (int)q5.y, (int)q5.z};
  const int   pc[7] = {(int)q6.x, (int)q6.y, (int)q6.z, (int)q6.w, (int)q7.x, (int)q7.y, (int)q7.z};

  if (lane == 0) {
    sArr[row] = q0.x + q0.y + q0.z + q0.w + q1.x + q1.y + q1.z
              + q2.x + q2.y + q2.z + q2.w + q3.x + q3.y + q3.z;
  }

  const __hip_bfloat16* xpn = xbb + ((size_t)n * L_DIM) * C_DIM;
  __hip_bfloat16* so = gb + (size_t)row * C_DIM;

#pragma unroll
  for (int j = 0; j < 2; j++) {
    const int c8 = j * 512 + lane * 8;
    float a[8] = {0.f, 0.f, 0.f, 0.f, 0.f, 0.f, 0.f, 0.f};
#pragma unroll
    for (int k = 0; k < 7; k++) {
      union { int4 q; __hip_bfloat16 h[8]; } uf, uc;
      uf.q = *(const int4*)(xpn + (size_t)pf[k] * C_DIM + c8);
      uc.q = *(const int4*)(xpn + (size_t)pc[k] * C_DIM + c8);
#pragma unroll
      for (int t = 0; t < 8; t++)
        a[t] += wf[k] * (float)uf.h[t] + wc[k] * (float)uc.h[t];
    }
    union { int4 q; __hip_bfloat16 h[8]; } uo;
#pragma unroll
    for (int t = 0; t < 8; t++) uo.h[t] = __float2bfloat16(a[t]);
    *(int4*)(so + c8) = uo.q;
  }
}

// ------- mid v4 kept for small-workspace fallback paths -------
__global__ __launch_bounds__(256)
void mid_fused_v4(const float* __restrict__ x,
                  const float* __restrict__ dw_w, const float* __restrict__ dw_b,
                  const float* __restrict__ ln_g, const float* __restrict__ ln_b,
                  const float* __restrict__ Wo,   const float* __restrict__ bo,
                  const float* __restrict__ Wm,   const float* __restrict__ bmb,
                  const __hip_bfloat16* __restrict__ xp,
                  __hip_bfloat16* __restrict__ smp)
{
  const int b    = blockIdx.x;
  const int bs   = (b & 7) * 256 + (b >> 3);
  const int wid  = threadIdx.x >> 6;
  const int lane = threadIdx.x & 63;
  const int row  = bs * 4 + wid;
  const int l    = row & (L_DIM - 1);
  const int n    = row >> 11;

  const float* xr = x + (size_t)row * C_DIM;

  float4 v[4];
#pragma unroll
  for (int j = 0; j < 4; j++) {
    const int c4 = j * 256 + lane * 4;
    const float4 x0 = *(const float4*)(xr + c4);
    float4 xm = make_float4(0.f, 0.f, 0.f, 0.f);
    float4 xq = make_float4(0.f, 0.f, 0.f, 0.f);
    if (l > 0)         xm = *(const float4*)(xr + c4 - C_DIM);
    if (l < L_DIM - 1) xq = *(const float4*)(xr + c4 + C_DIM);
    const float4 w0 = *(const float4*)(dw_w + (size_t)c4 * 3);
    const float4 w1 = *(const float4*)(dw_w + (size_t)c4 * 3 + 4);
    const float4 w2 = *(const float4*)(dw_w + (size_t)c4 * 3 + 8);
    const float4 bb = *(const float4*)(dw_b + c4);
    v[j].x = xm.x * w0.x + x0.x * w0.y + xq.x * w0.z + bb.x;
    v[j].y = xm.y * w0.w + x0.y * w1.x + xq.y * w1.y + bb.y;
    v[j].z = xm.z * w1.z + x0.z * w1.w + xq.z * w2.x + bb.z;
    v[j].w = xm.w * w2.y + x0.w * w2.z + xq.w * w2.w + bb.w;
  }

  float s1 = 0.f, s2 = 0.f;
#pragma unroll
  for (int j = 0; j < 4; j++) {
    s1 += v[j].x + v[j].y + v[j].z + v[j].w;
    s2 += v[j].x * v[j].x + v[j].y * v[j].y + v[j].z * v[j].z + v[j].w * v[j].w;
  }
#pragma unroll
  for (int m = 1; m < 64; m <<= 1) { s1 += __shfl_xor(s1, m); s2 += __shfl_xor(s2, m); }
  const float mu   = s1 * (1.f / C_DIM);
  const float rstd = rsqrtf(s2 * (1.f / C_DIM) - mu * mu + 1e-5f);

  float4 g[4];
#pragma unroll
  for (int j = 0; j < 4; j++) {
    const int c4 = j * 256 + lane * 4;
    const float4 gg = *(const float4*)(ln_g + c4);
    const float4 bb = *(const float4*)(ln_b + c4);
    g[j].x = gelu_fast((v[j].x - mu) * rstd * gg.x + bb.x);
    g[j].y = gelu_fast((v[j].y - mu) * rstd * gg.y + bb.y);
    g[j].z = gelu_fast((v[j].z - mu) * rstd * gg.z + bb.z);
    g[j].w = gelu_fast((v[j].w - mu) * rstd * gg.w + bb.w);
  }

  float po[7] = {0,0,0,0,0,0,0}, pm[7] = {0,0,0,0,0,0,0};
#pragma unroll
  for (int k = 0; k < 7; k++) {
#pragma unroll
    for (int j = 0; j < 4; j++) {
      const int c4 = j * 256 + lane * 4;
      const float4 wo = *(const float4*)(Wo + (size_t)k * C_DIM + c4);
      const float4 wm = *(const float4*)(Wm + (size_t)k * C_DIM + c4);
      po[k] += g[j].x * wo.x + g[j].y * wo.y + g[j].z * wo.z + g[j].w * wo.w;
      pm[k] += g[j].x * wm.x + g[j].y * wm.y + g[j].z * wm.z + g[j].w * wm.w;
    }
  }
#pragma unroll
  for (int k = 0; k < 7; k++)
#pragma unroll
    for (int m = 1; m < 64; m <<= 1) {
      po[k] += __shfl_xor(po[k], m);
      pm[k] += __shfl_xor(pm[k], m);
    }

  float lg[7], mx = -1e30f;
#pragma unroll
  for (int k = 0; k < 7; k++) { lg[k] = pm[k] + bmb[k]; mx = fmaxf(mx, lg[k]); }
  float se = 0.f, e[7];
#pragma unroll
  for (int k = 0; k < 7; k++) { e[k] = __expf(lg[k] - mx); se += e[k]; }
  const float inv = 1.f / se;

  float wf[7], wcl[7]; int pf[7], pc[7];
#pragma unroll
  for (int k = 0; k < 7; k++) {
    const float msk = e[k] * inv;
    const float off = (po[k] + bo[k]) * 2.0f;
    const float ap  = (float)l + (float)(k - 3) + off;
    const float apc = fminf(fmaxf(ap, 0.f), (float)(L_DIM - 1));
    int f = (int)apc;
    int c = f + 1; if (c > L_DIM - 1) c = L_DIM - 1;
    const float w1  = apc - (float)f;
    const float val = (ap < 0.f || ap > (float)(L_DIM - 1)) ? 0.f : 1.f;
    wf[k]  = (1.f - w1) * val * msk;
    wcl[k] = w1 * val * msk;
    pf[k] = f; pc[k] = c;
  }

  const __hip_bfloat16* xpn = xp + ((size_t)n * L_DIM) * C_DIM;
  __hip_bfloat16* so = smp + (size_t)row * C_DIM;
#pragma unroll
  for (int j = 0; j < 4; j++) {
    const int c4 = j * 256 + lane * 4;
    float4 a = make_float4(0.f, 0.f, 0.f, 0.f);
#pragma unroll
    for (int k = 0; k < 7; k++) {
      const float4 vf = ldbf4(xpn + (size_t)pf[k] * C_DIM + c4);
      const float4 vc = ldbf4(xpn + (size_t)pc[k] * C_DIM + c4);
      a.x += wf[k] * vf.x + wcl[k] * vc.x;
      a.y += wf[k] * vf.y + wcl[k] * vc.y;
      a.z += wf[k] * vf.z + wcl[k] * vc.z;
      a.w += wf[k] * vf.w + wcl[k] * vc.w;
    }
    stbf4(so + c4, a);
  }
}

// ---------------- host ----------------
extern "C" void kernel_launch(void* const* d_in, const int* in_sizes, int n_in,
                              void* d_out, int out_size, void* d_ws, size_t ws_size,
                              hipStream_t stream)
{
  const float* x    = (const float*)d_in[0];
  const float* Wi   = (const float*)d_in[1];
  const float* bi   = (const float*)d_in[2];
  const float* dw_w = (const float*)d_in[3];
  const float* dw_b = (const float*)d_in[4];
  const float* ln_g = (const float*)d_in[5];
  const float* ln_b = (const float*)d_in[6];
  const float* Wo   = (const float*)d_in[7];
  const float* bo   = (const float*)d_in[8];
  const float* Wm   = (const float*)d_in[9];
  const float* bm   = (const float*)d_in[10];
  const float* Wout = (const float*)d_in[11];
  const float* bout = (const float*)d_in[12];
  float* out = (float*)d_out;

  const size_t XE = (size_t)M_DIM * C_DIM;
  const size_t WE = (size_t)C_DIM * C_DIM;
  char* wsb = (char*)d_ws;

  // ---- collapsed-GEMM path layout ----
  __hip_bfloat16* xbb2  = (__hip_bfloat16*)wsb;                       // XE*2
  __hip_bfloat16* gb    = (__hip_bfloat16*)(wsb + XE * 2);            // XE*2
  __hip_bfloat16* Woutb2= (__hip_bfloat16*)(wsb + XE * 4);            // WE*2
  __hip_bfloat16* WiT   = (__hip_bfloat16*)(wsb + XE * 4 + WE * 2);   // WE*2
  __hip_bfloat16* Wcb   = (__hip_bfloat16*)(wsb + XE * 4 + WE * 4);   // WE*2
  float* coef2 = (float*)(wsb + XE * 4 + WE * 6);                     // M*128
  float* sArr  = (float*)(wsb + XE * 4 + WE * 6 + (size_t)M_DIM * 128);
  float* bvec  = (float*)(wsb + XE * 4 + WE * 6 + (size_t)M_DIM * 128 + (size_t)M_DIM * 4);
  const size_t need_v5 = XE * 4 + WE * 6 + (size_t)M_DIM * 132 + 4096;

  // ---- legacy layouts (fallbacks) ----
  __hip_bfloat16* xp    = (__hip_bfloat16*)wsb;
  __hip_bfloat16* smp   = (__hip_bfloat16*)(wsb + XE * 2);
  __hip_bfloat16* Wib   = (__hip_bfloat16*)(wsb + XE * 4);
  __hip_bfloat16* Woutb = (__hip_bfloat16*)(wsb + XE * 4 + WE * 2);
  __hip_bfloat16* xbb   = (__hip_bfloat16*)(wsb + XE * 4 + WE * 4);
  const size_t need_w2   = XE * 4 + WE * 4;
  const size_t need_full = need_w2 + XE * 2;

  dim3 gg(M_DIM / 128, C_DIM / 128);   // 64 x 8

  if (ws_size >= need_v5) {
    // 3-launch collapsed pipeline:
    //   L1: aux (WiT/Woutb/bvec, blocks 0..767) + pre_fused v2 (768..1279)
    //   L2: Wcomb GEMM (64 blk) + gather (1024 blk)
    //   L3: out = gb @ Wcb^T + sArr*bvec + bout
    pre_aux<<<1280, 256, 0, stream>>>(
        x, dw_w, dw_b, ln_g, ln_b, Wo, bo, Wm, bm,
        Wi, Wout, bi, xbb2, coef2, WiT, Woutb2, bvec);
    wcomb_gather<<<1088, 512, 0, stream>>>(
        Woutb2, WiT, Wcb, coef2, xbb2, gb, sArr);
    gemm_db<float><<<gg, 256, 0, stream>>>(
        gb, Wcb, bout, out, M_DIM, C_DIM, C_DIM, sArr, bvec);
  } else if (ws_size >= need_full) {
    cvt_f32_bf16<<<(int)(XE / 8 / 256), 256, 0, stream>>>(x, xbb, (int)(XE / 8));
    cvt_two_f32_bf16<<<(int)(2 * (WE / 8) / 256), 256, 0, stream>>>(
        Wi, Wib, Wout, Woutb, (int)(WE / 8));
    gemm_db<__hip_bfloat16><<<gg, 256, 0, stream>>>(xbb, Wib, bi, xp, M_DIM, C_DIM, C_DIM,
                                                    nullptr, nullptr);
    mid_fused_v4<<<M_DIM / 4, 256, 0, stream>>>(x, dw_w, dw_b, ln_g, ln_b, Wo, bo, Wm, bm, xp, smp);
    gemm_db<float><<<gg, 256, 0, stream>>>(smp, Woutb, bout, out, M_DIM, C_DIM, C_DIM,
                                           nullptr, nullptr);
  } else if (ws_size >= need_w2) {
    cvt_f32_bf16<<<(int)(WE / 8 / 256), 256, 0, stream>>>(Wout, Woutb, (int)(WE / 8));
    gemm_nt<float, __hip_bfloat16><<<gg, 256, 0, stream>>>(x, Wi, bi, xp, M_DIM, C_DIM, C_DIM);
    mid_fused_v4<<<M_DIM / 4, 256, 0, stream>>>(x, dw_w, dw_b, ln_g, ln_b, Wo, bo, Wm, bm, xp, smp);
    gemm_db<float><<<gg, 256, 0, stream>>>(smp, Woutb, bout, out, M_DIM, C_DIM, C_DIM,
                                           nullptr, nullptr);
  } else {
    gemm_nt<float, __hip_bfloat16><<<gg, 256, 0, stream>>>(x, Wi, bi, xp, M_DIM, C_DIM, C_DIM);
    mid_fused_v4<<<M_DIM / 4, 256, 0, stream>>>(x, dw_w, dw_b, ln_g, ln_b, Wo, bo, Wm, bm, xp, smp);
    gemm_nt<__hip_bfloat16, float><<<gg, 256, 0, stream>>>(smp, Wout, bout, out, M_DIM, C_DIM, C_DIM);
  }
}